// Round 8
// baseline (571.416 us; speedup 1.0000x reference)
//
#include <hip/hip_runtime.h>
#include <hip/hip_bf16.h>
#include <stdint.h>

#define NW   1024
#define D    768
#define NS   8192
#define MAXW 30
#define FFNN 1000
#define FEAT 20

typedef __attribute__((ext_vector_type(8))) short bf16x8;
typedef __attribute__((ext_vector_type(4))) float f32x4;
#define MFMA16 __builtin_amdgcn_mfma_f32_16x16x32_bf16

// ws layout (float-slot offsets)
#define O_P    0                          // 3*1024*1000 fp32 P1,P2,P3
#define O_P4   3072000                    // 30*1000
#define O_HS   3102000                    // 1024
#define O_ATT  3103024                    // 8192*32 (ATT; later SEL/SELKEY/CNT)
#define O_PS   3365168                    // 8192*16
#define O_H1R  3504432                    // H1 hi/lo bf16; later pk[8192] u64

__device__ inline ushort f2b(float v) {
    __hip_bfloat16 b = __float2bfloat16(v);
    return *(ushort*)&b;
}
__device__ inline float b2f(ushort u) {
    __hip_bfloat16 b = *(__hip_bfloat16*)&u;
    return __bfloat162float(b);
}

// ---------- head scores ----------
__global__ __launch_bounds__(256) void k_head(const float* __restrict__ doc,
                                              const float* __restrict__ wh,
                                              const float* __restrict__ bh,
                                              float* __restrict__ hs) {
    int wid = threadIdx.x >> 6, lane = threadIdx.x & 63;
    int word = blockIdx.x * 4 + wid;
    const float* row = doc + word * D;
    float acc = 0.f;
    for (int d = lane; d < D; d += 64) acc += row[d] * wh[d];
    #pragma unroll
    for (int o = 32; o; o >>= 1) acc += __shfl_down(acc, o);
    if (lane == 0) hs[word] = acc + bh[0];
}

// ---------- P4 = w_width_emb @ W1[1536:1556,:] ----------
__global__ __launch_bounds__(256) void k_p4(const float* __restrict__ wwe,
                                            const float* __restrict__ W1,
                                            float* __restrict__ P4) {
    int o = blockIdx.x * 256 + threadIdx.x;
    if (o >= 30 * FFNN) return;
    int wi = o / FFNN, j = o - wi * FFNN;
    float acc = 0.f;
    #pragma unroll
    for (int f = 0; f < FEAT; ++f) acc += wwe[wi * FEAT + f] * W1[(1536 + f) * FFNN + j];
    P4[o] = acc;
}

// ---------- split fp32 -> bf16 hi/lo ----------
__global__ __launch_bounds__(256) void k_split(const float* __restrict__ src,
                                               ushort* __restrict__ h,
                                               ushort* __restrict__ l, int n) {
    int i = blockIdx.x * 256 + threadIdx.x;
    if (i >= n) return;
    float v = src[i];
    ushort hi = f2b(v);
    float r = v - b2f(hi);
    h[i] = hi;
    l[i] = f2b(r);
}

// ---------- W1 slices: transpose + split -> W1T[z][1024 n][768 k] hi/lo ----------
__global__ void k_tw1(const float* __restrict__ W1,
                      ushort* __restrict__ TH, ushort* __restrict__ TL) {
    __shared__ float tile[32][33];
    int tx = threadIdx.x, ty = threadIdx.y;
    int k0 = blockIdx.x * 32, n0 = blockIdx.y * 32, z = blockIdx.z;
    int roff = (z == 0) ? 0 : (z == 1) ? 768 : 1556;
    #pragma unroll
    for (int i = 0; i < 4; ++i) {
        int kk = ty + i * 8;
        float v = (n0 + tx < FFNN) ? W1[(size_t)(roff + k0 + kk) * FFNN + n0 + tx] : 0.f;
        tile[kk][tx] = v;
    }
    __syncthreads();
    #pragma unroll
    for (int i = 0; i < 4; ++i) {
        int nn = ty + i * 8;
        float v = tile[tx][nn];
        ushort hi = f2b(v);
        float r = v - b2f(hi);
        size_t o = (size_t)z * 1024 * D + (size_t)(n0 + nn) * D + k0 + tx;
        TH[o] = hi;
        TL[o] = f2b(r);
    }
}

// ---------- W2: transpose + split -> W2T[1024 n][1000 k] hi/lo ----------
__global__ void k_tw2(const float* __restrict__ W2,
                      ushort* __restrict__ TH, ushort* __restrict__ TL) {
    __shared__ float tile[32][33];
    int tx = threadIdx.x, ty = threadIdx.y;
    int k0 = blockIdx.x * 32, n0 = blockIdx.y * 32;
    #pragma unroll
    for (int i = 0; i < 4; ++i) {
        int kk = ty + i * 8;
        float v = (k0 + kk < FFNN && n0 + tx < FFNN)
                    ? W2[(size_t)(k0 + kk) * FFNN + n0 + tx] : 0.f;
        tile[kk][tx] = v;
    }
    __syncthreads();
    #pragma unroll
    for (int i = 0; i < 4; ++i) {
        int nn = ty + i * 8;
        int k = k0 + tx;
        if (k < FFNN) {
            float v = tile[tx][nn];
            ushort hi = f2b(v);
            float r = v - b2f(hi);
            size_t o = (size_t)(n0 + nn) * FFNN + k;
            TH[o] = hi;
            TL[o] = f2b(r);
        }
    }
}

// ---------- MFMA GEMM: P[z] = doc @ W1slice  (split-bf16 3-term, 128x128 tile) ----------
__global__ __launch_bounds__(256) void k_gemmPm(const ushort* __restrict__ Ah_g,
                                                const ushort* __restrict__ Al_g,
                                                const ushort* __restrict__ Bh_g,
                                                const ushort* __restrict__ Bl_g,
                                                float* __restrict__ Pout) {
    __shared__ ushort Ah[128][40], Al[128][40], Bh[128][40], Bl[128][40];
    int tid = threadIdx.x;
    int row0 = blockIdx.y * 128, col0 = blockIdx.x * 128;
    size_t zoff = (size_t)blockIdx.z * 1024 * D;
    const ushort* Bh_z = Bh_g + zoff;
    const ushort* Bl_z = Bl_g + zoff;
    float* C = Pout + (size_t)blockIdx.z * NW * FFNN;
    int w = tid >> 6, l = tid & 63;
    int wr = w >> 1, wc = w & 1;
    int fr = l & 15, kb = l >> 4;
    f32x4 acc[4][4] = {};
    for (int kt = 0; kt < D; kt += 32) {
        #pragma unroll
        for (int i = 0; i < 2; ++i) {
            int cid = tid + i * 256;
            int r = cid >> 2, kc = cid & 3;
            int kg = kt + kc * 8;
            uint4 a0 = *(const uint4*)(Ah_g + (size_t)(row0 + r) * D + kg);
            uint4 a1 = *(const uint4*)(Al_g + (size_t)(row0 + r) * D + kg);
            uint4 b0 = *(const uint4*)(Bh_z + (size_t)(col0 + r) * D + kg);
            uint4 b1 = *(const uint4*)(Bl_z + (size_t)(col0 + r) * D + kg);
            *(uint4*)&Ah[r][kc * 8] = a0;
            *(uint4*)&Al[r][kc * 8] = a1;
            *(uint4*)&Bh[r][kc * 8] = b0;
            *(uint4*)&Bl[r][kc * 8] = b1;
        }
        __syncthreads();
        bf16x8 af[4], alf[4], bfr[4], blf[4];
        #pragma unroll
        for (int mt = 0; mt < 4; ++mt) {
            int r = wr * 64 + mt * 16 + fr;
            af[mt]  = *(const bf16x8*)&Ah[r][kb * 8];
            alf[mt] = *(const bf16x8*)&Al[r][kb * 8];
        }
        #pragma unroll
        for (int nt = 0; nt < 4; ++nt) {
            int c = wc * 64 + nt * 16 + fr;
            bfr[nt] = *(const bf16x8*)&Bh[c][kb * 8];
            blf[nt] = *(const bf16x8*)&Bl[c][kb * 8];
        }
        #pragma unroll
        for (int mt = 0; mt < 4; ++mt)
            #pragma unroll
            for (int nt = 0; nt < 4; ++nt) {
                acc[mt][nt] = MFMA16(af[mt], bfr[nt], acc[mt][nt], 0, 0, 0);
                acc[mt][nt] = MFMA16(af[mt], blf[nt], acc[mt][nt], 0, 0, 0);
                acc[mt][nt] = MFMA16(alf[mt], bfr[nt], acc[mt][nt], 0, 0, 0);
            }
        __syncthreads();
    }
    #pragma unroll
    for (int mt = 0; mt < 4; ++mt)
        #pragma unroll
        for (int nt = 0; nt < 4; ++nt)
            #pragma unroll
            for (int r = 0; r < 4; ++r) {
                int row = row0 + wr * 64 + mt * 16 + kb * 4 + r;
                int col = col0 + wc * 64 + nt * 16 + fr;
                if (col < FFNN) C[(size_t)row * FFNN + col] = acc[mt][nt][r];
            }
}

// ---------- MFMA GEMM2 fused: relu(H1@W2+b2).W3 -> PS  (split-bf16, 128x128) ----------
__global__ __launch_bounds__(256) void k_gemm2m(const ushort* __restrict__ Ah_g,
                                                const ushort* __restrict__ Al_g,
                                                const ushort* __restrict__ Bh_g,
                                                const ushort* __restrict__ Bl_g,
                                                const float* __restrict__ b2,
                                                const float* __restrict__ W3,
                                                float* __restrict__ PS) {
    __shared__ ushort Ah[128][40], Al[128][40], Bh[128][40], Bl[128][40];
    int tid = threadIdx.x;
    int row0 = blockIdx.y * 128, col0 = blockIdx.x * 128;
    int w = tid >> 6, l = tid & 63;
    int wr = w >> 1, wc = w & 1;
    int fr = l & 15, kb = l >> 4;
    f32x4 acc[4][4] = {};
    for (int kt = 0; kt < FFNN; kt += 32) {
        #pragma unroll
        for (int i = 0; i < 2; ++i) {
            int cid = tid + i * 256;
            int r = cid >> 2, kc = cid & 3;
            int kg = kt + kc * 8;
            bool v = (kg + 7) < FFNN;
            uint4 z = make_uint4(0, 0, 0, 0);
            uint4 a0 = v ? *(const uint4*)(Ah_g + (size_t)(row0 + r) * FFNN + kg) : z;
            uint4 a1 = v ? *(const uint4*)(Al_g + (size_t)(row0 + r) * FFNN + kg) : z;
            uint4 b0 = v ? *(const uint4*)(Bh_g + (size_t)(col0 + r) * FFNN + kg) : z;
            uint4 b1 = v ? *(const uint4*)(Bl_g + (size_t)(col0 + r) * FFNN + kg) : z;
            *(uint4*)&Ah[r][kc * 8] = a0;
            *(uint4*)&Al[r][kc * 8] = a1;
            *(uint4*)&Bh[r][kc * 8] = b0;
            *(uint4*)&Bl[r][kc * 8] = b1;
        }
        __syncthreads();
        bf16x8 af[4], alf[4], bfr[4], blf[4];
        #pragma unroll
        for (int mt = 0; mt < 4; ++mt) {
            int r = wr * 64 + mt * 16 + fr;
            af[mt]  = *(const bf16x8*)&Ah[r][kb * 8];
            alf[mt] = *(const bf16x8*)&Al[r][kb * 8];
        }
        #pragma unroll
        for (int nt = 0; nt < 4; ++nt) {
            int c = wc * 64 + nt * 16 + fr;
            bfr[nt] = *(const bf16x8*)&Bh[c][kb * 8];
            blf[nt] = *(const bf16x8*)&Bl[c][kb * 8];
        }
        #pragma unroll
        for (int mt = 0; mt < 4; ++mt)
            #pragma unroll
            for (int nt = 0; nt < 4; ++nt) {
                acc[mt][nt] = MFMA16(af[mt], bfr[nt], acc[mt][nt], 0, 0, 0);
                acc[mt][nt] = MFMA16(af[mt], blf[nt], acc[mt][nt], 0, 0, 0);
                acc[mt][nt] = MFMA16(alf[mt], bfr[nt], acc[mt][nt], 0, 0, 0);
            }
        __syncthreads();
    }
    float w3v[4], b2v[4];
    #pragma unroll
    for (int nt = 0; nt < 4; ++nt) {
        int col = col0 + wc * 64 + nt * 16 + fr;
        bool cv = col < FFNN;
        w3v[nt] = cv ? W3[col] : 0.f;
        b2v[nt] = cv ? b2[col] : 0.f;
    }
    #pragma unroll
    for (int mt = 0; mt < 4; ++mt) {
        #pragma unroll
        for (int r = 0; r < 4; ++r) {
            float p = 0.f;
            #pragma unroll
            for (int nt = 0; nt < 4; ++nt) {
                float v = fmaxf(acc[mt][nt][r] + b2v[nt], 0.f);
                p = fmaf(v, w3v[nt], p);
            }
            p += __shfl_xor(p, 1);
            p += __shfl_xor(p, 2);
            p += __shfl_xor(p, 4);
            p += __shfl_xor(p, 8);
            if (fr == 0) {
                int row = row0 + wr * 64 + mt * 16 + kb * 4 + r;
                PS[row * 16 + blockIdx.x * 2 + wc] = p;
            }
        }
    }
}

// ---------- attention weights per span ----------
__global__ __launch_bounds__(256) void k_attn(const float* __restrict__ hs,
                                              const int* __restrict__ starts,
                                              const int* __restrict__ ends,
                                              float* __restrict__ attn) {
    int s = blockIdx.x * 256 + threadIdx.x;
    if (s >= NS) return;
    int st = starts[s], en = ends[s];
    int width = en - st + 1;
    float v[MAXW];
    float mx = -3.0e38f;
    #pragma unroll
    for (int w = 0; w < MAXW; ++w) {
        int idx = st + w; if (idx > NW - 1) idx = NW - 1;
        float x = hs[idx];
        v[w] = (w < width) ? x : -3.0e38f;
        mx = fmaxf(mx, v[w]);
    }
    float sum = 0.f;
    #pragma unroll
    for (int w = 0; w < MAXW; ++w) { v[w] = expf(v[w] - mx); sum += v[w]; }
    float inv = 1.f / sum;
    #pragma unroll
    for (int w = 0; w < MAXW; ++w) attn[s * 32 + w] = v[w] * inv;
}

// ---------- h1 assembly: gather P rows + attended + bias + relu -> bf16 hi/lo ----------
__global__ __launch_bounds__(256) void k_h1(const float* __restrict__ P,
                                            const float* __restrict__ P4,
                                            const float* __restrict__ attn,
                                            const float* __restrict__ b1,
                                            const int* __restrict__ starts,
                                            const int* __restrict__ ends,
                                            ushort* __restrict__ H1h,
                                            ushort* __restrict__ H1l) {
    int s = blockIdx.x;
    int tid = threadIdx.x;
    if (tid >= 250) return;
    int st = starts[s], en = ends[s];
    int width = en - st + 1;
    const float4* P1r = (const float4*)(P + (size_t)st * FFNN);
    const float4* P2r = (const float4*)(P + (size_t)NW * FFNN + (size_t)en * FFNN);
    const float*  P3  = P + 2 * (size_t)NW * FFNN;
    const float4* P4r = (const float4*)(P4 + (size_t)(width - 1) * FFNN);
    const float4* b1v = (const float4*)b1;
    const float*  ar  = attn + s * 32;
    float4 a = P1r[tid], b = P2r[tid], c = P4r[tid], d = b1v[tid];
    float4 acc = {a.x + b.x + c.x + d.x,
                  a.y + b.y + c.y + d.y,
                  a.z + b.z + c.z + d.z,
                  a.w + b.w + c.w + d.w};
    for (int w = 0; w < width; ++w) {
        float aw = ar[w];
        float4 p3 = ((const float4*)(P3 + (size_t)(st + w) * FFNN))[tid];
        acc.x = fmaf(aw, p3.x, acc.x);
        acc.y = fmaf(aw, p3.y, acc.y);
        acc.z = fmaf(aw, p3.z, acc.z);
        acc.w = fmaf(aw, p3.w, acc.w);
    }
    float rv[4] = {fmaxf(acc.x, 0.f), fmaxf(acc.y, 0.f), fmaxf(acc.z, 0.f), fmaxf(acc.w, 0.f)};
    ushort4 hi, lo;
    ushort* hp = (ushort*)&hi;
    ushort* lp = (ushort*)&lo;
    #pragma unroll
    for (int j = 0; j < 4; ++j) {
        ushort h = f2b(rv[j]);
        float r = rv[j] - b2f(h);
        hp[j] = h;
        lp[j] = f2b(r);
    }
    *(ushort4*)(H1h + (size_t)s * FFNN + tid * 4) = hi;
    *(ushort4*)(H1l + (size_t)s * FFNN + tid * 4) = lo;
}

// ---------- final score: sum 16 partials + b3 ----------
__global__ __launch_bounds__(256) void k_score2(const float* __restrict__ PS,
                                                const float* __restrict__ b3,
                                                float* __restrict__ out) {
    int r = blockIdx.x * 256 + threadIdx.x;
    if (r >= NS) return;
    float s = 0.f;
    #pragma unroll
    for (int b = 0; b < 16; ++b) s += PS[r * 16 + b];
    out[r] = s + b3[0];
}

// ---------- exact descending argsort; emits packed (span,s,e) per rank ----------
__global__ __launch_bounds__(256) void k_rank(const float* __restrict__ scores,
                                              const int* __restrict__ starts,
                                              const int* __restrict__ ends,
                                              unsigned long long* __restrict__ pk) {
    __shared__ unsigned long long tile[256];
    int i = blockIdx.x * 256 + threadIdx.x;
    unsigned u = __float_as_uint(scores[i]);
    unsigned m = (u >> 31) ? ~u : (u | 0x80000000u);
    unsigned long long key = ((unsigned long long)(~m) << 32) | (unsigned)i;
    int rank = 0;
    for (int t = 0; t < NS / 256; ++t) {
        int j = t * 256 + threadIdx.x;
        unsigned uj = __float_as_uint(scores[j]);
        unsigned mj = (uj >> 31) ? ~uj : (uj | 0x80000000u);
        tile[threadIdx.x] = ((unsigned long long)(~mj) << 32) | (unsigned)j;
        __syncthreads();
        #pragma unroll 8
        for (int q = 0; q < 256; ++q) rank += (tile[q] < key);
        __syncthreads();
    }
    int st = starts[i], en = ends[i];
    pk[rank] = ((unsigned long long)(unsigned)i << 32) |
               ((unsigned)st << 16) | (unsigned)en;
}

// ---------- greedy crossing-suppression scan (no sort; emits SEL/SELKEY/CNT) ----------
// O(1) global cross check (mxs/mne/mxe) + ballot-round in-chunk resolution with
// hybrid pairwise-mask build: readlane loop (few candidates) or 63-rotation
// shfl build (many candidates, pure VALU, no ballots).
__global__ __launch_bounds__(64) void k_scan(const unsigned long long* __restrict__ pk,
                                             int top, int* __restrict__ SEL,
                                             int* __restrict__ SELKEY,
                                             int* __restrict__ CNT) {
    __shared__ int mxs[NW];    // max start among accepted straddling gap p->p+1
    __shared__ int mne[NW];    // min end among accepted with s'' < p <= e''
    __shared__ int mxe[NW];    // max end among accepted starting exactly at p
    int lane = threadIdx.x;
    unsigned long long lower = (1ull << lane) - 1ull;
    for (int p = lane; p < NW; p += 64) { mxs[p] = -1; mne[p] = NW; mxe[p] = -1; }
    __syncthreads();
    int count = 0;
    unsigned long long pc = pk[lane];
    for (int c = 0; c < NS / 64 && count < top; ++c) {
        unsigned long long pn = 0;
        if (c + 1 < NS / 64) pn = pk[(c + 1) * 64 + lane];   // prefetch
        int span = (int)(pc >> 32);
        int s = (int)((pc >> 16) & 0xFFFF);
        int e = (int)(pc & 0xFFFF);
        int bad = (mxs[e] > s) | (mne[s] < e);   // exact global cross check
        int g = mxe[s];
        bool gdup = (g == e), ggt = (g > e);
        unsigned long long M = __ballot(!bad);
        if (M) {
            unsigned long long conf = 0, eqm = 0, gtm = 0;
            int nM = __popcll(M);
            if (nM <= 10) {
                unsigned long long t = M;
                while (t) {
                    int i = __builtin_ctzll(t); t &= t - 1;
                    int si = __builtin_amdgcn_readlane(s, i);
                    int ei = __builtin_amdgcn_readlane(e, i);
                    unsigned long long bit = 1ull << i;
                    if (((si > s) & (si <= e) & (ei > e)) |
                        ((ei >= s) & (ei < e) & (si < s))) conf |= bit;
                    if (si == s) { if (ei == e) eqm |= bit; else if (ei > e) gtm |= bit; }
                }
            } else {
                for (int r = 1; r < 64; ++r) {
                    int j = (lane + r) & 63;
                    int sj = __shfl(s, j);
                    int ej = __shfl(e, j);
                    bool inM = (M >> j) & 1;
                    unsigned long long bit = 1ull << j;
                    bool cross = ((sj > s) & (sj <= e) & (ej > e)) |
                                 ((ej >= s) & (ej < e) & (sj < s));
                    if (inM & cross) conf |= bit;
                    if (inM & (sj == s)) {
                        if (ej == e) eqm |= bit;
                        else if (ej > e) gtm |= bit;
                    }
                }
            }
            // ballot-only sequential-order resolution (R3-proven)
            unsigned long long pending = M, committed = 0;
            while (pending) {
                bool mine = (pending >> lane) & 1;
                unsigned long long relv = (conf | eqm | gtm) & lower;
                bool ready = mine && ((pending & relv) == 0ull);
                unsigned long long cb = committed & lower;
                bool rej = (cb & conf) != 0ull;
                bool gt_any = ggt || ((cb & gtm) != 0ull);
                bool eq_any = gdup || ((cb & eqm) != 0ull);
                bool acc_now = ready && !rej && !(eq_any && !gt_any);
                committed |= __ballot(acc_now);
                pending &= ~__ballot(ready);
            }
            // cap at top
            int allowed = top - count;
            while (__popcll(committed) > allowed)
                committed &= ~(1ull << (63 - __builtin_clzll(committed)));
            // commit processing: emit + state range updates
            unsigned long long cb2 = committed;
            while (cb2) {
                int i = __builtin_ctzll(cb2); cb2 &= cb2 - 1;
                int sj = __builtin_amdgcn_readlane(s, i);
                int ej = __builtin_amdgcn_readlane(e, i);
                int spj = __builtin_amdgcn_readlane(span, i);
                if (lane == 0) {
                    SEL[count] = spj;
                    SELKEY[count] = sj * NW + ej;
                    if (ej > mxe[sj]) mxe[sj] = ej;
                }
                if (lane < ej - sj) {
                    atomicMax(&mxs[sj + lane], sj);
                    atomicMin(&mne[sj + 1 + lane], ej);
                }
                ++count;
            }
        }
        __syncthreads();
        pc = pn;
    }
    if (lane == 0) *CNT = count;
}

// ---------- final sort: multi-wave rank sort of the selected spans ----------
__global__ __launch_bounds__(512) void k_sort(const int* __restrict__ SEL,
                                              const int* __restrict__ SELKEY,
                                              const int* __restrict__ CNT,
                                              int top, float* __restrict__ out_idx) {
    __shared__ int keys[512];
    __shared__ int vals[512];
    int cnt = *CNT;
    int r = threadIdx.x;
    if (r < top) {
        keys[r] = (r < cnt) ? SELKEY[r] : NW * NW;
        vals[r] = (r < cnt) ? SEL[r] : -1;
    }
    __syncthreads();
    if (r < top) {
        int kr = keys[r];
        int rank = 0;
        for (int q = 0; q < top; ++q) {
            int kq = keys[q];
            rank += (kq < kr) || (kq == kr && q < r);
        }
        out_idx[rank] = (float)vals[r];
    }
}

extern "C" void kernel_launch(void* const* d_in, const int* in_sizes, int n_in,
                              void* d_out, int out_size, void* d_ws, size_t ws_size,
                              hipStream_t stream) {
    const float* doc = (const float*)d_in[0];
    const float* wwe = (const float*)d_in[1];
    const float* wh  = (const float*)d_in[2];
    const float* bh  = (const float*)d_in[3];
    const float* W1  = (const float*)d_in[4];
    const float* b1  = (const float*)d_in[5];
    const float* W2  = (const float*)d_in[6];
    const float* b2  = (const float*)d_in[7];
    const float* W3  = (const float*)d_in[8];
    const float* b3  = (const float*)d_in[9];
    const int* starts = (const int*)d_in[10];
    const int* ends   = (const int*)d_in[11];
    int top = out_size - NS;                 // 409

    float* ws  = (float*)d_ws;
    float* P   = ws + O_P;
    float* P4  = ws + O_P4;
    float* HS  = ws + O_HS;
    float* ATT = ws + O_ATT;
    float* PS  = ws + O_PS;
    float* H1R = ws + O_H1R;
    ushort* H1H = (ushort*)H1R;
    ushort* H1L = (ushort*)(H1R + 4096000);
    ushort* W1TH = (ushort*)H1R;
    ushort* W1TL = (ushort*)(H1R + 1179648);
    ushort* DOCH = (ushort*)(H1R + 2359296);
    ushort* DOCL = (ushort*)(H1R + 2752512);
    ushort* W2TH = (ushort*)ws;
    ushort* W2TL = (ushort*)(ws + 512000);
    unsigned long long* PK = (unsigned long long*)H1R;   // dead after k_gemm2m
    int* SEL    = (int*)(ws + O_ATT);                    // ATT dead after k_h1
    int* SELKEY = SEL + 512;
    int* CNT    = SEL + 1024;
    float* outs = (float*)d_out;

    k_head<<<NW / 4, 256, 0, stream>>>(doc, wh, bh, HS);
    k_p4<<<(30 * FFNN + 255) / 256, 256, 0, stream>>>(wwe, W1, P4);

    k_split<<<(NW * D + 255) / 256, 256, 0, stream>>>(doc, DOCH, DOCL, NW * D);
    {
        dim3 g(24, 32, 3), b(32, 8);
        k_tw1<<<g, b, 0, stream>>>(W1, W1TH, W1TL);
    }
    {
        dim3 g(8, 8, 3);
        k_gemmPm<<<g, 256, 0, stream>>>(DOCH, DOCL, W1TH, W1TL, P);
    }

    k_attn<<<NS / 256, 256, 0, stream>>>(HS, starts, ends, ATT);
    k_h1<<<NS, 256, 0, stream>>>(P, P4, ATT, b1, starts, ends, H1H, H1L);

    {
        dim3 g(32, 32), b(32, 8);
        k_tw2<<<g, b, 0, stream>>>(W2, W2TH, W2TL);
    }
    {
        dim3 g(8, NS / 128);
        k_gemm2m<<<g, 256, 0, stream>>>(H1H, H1L, W2TH, W2TL, b2, W3, PS);
    }

    k_score2<<<NS / 256, 256, 0, stream>>>(PS, b3, outs);
    k_rank<<<NS / 256, 256, 0, stream>>>(outs, starts, ends, PK);
    k_scan<<<1, 64, 0, stream>>>(PK, top, SEL, SELKEY, CNT);
    k_sort<<<1, 512, 0, stream>>>(SEL, SELKEY, CNT, top, outs + NS);
}

// Round 9
// 390.481 us; speedup vs baseline: 1.4634x; 1.4634x over previous
//
#include <hip/hip_runtime.h>
#include <hip/hip_bf16.h>
#include <stdint.h>

#define NW   1024
#define D    768
#define NS   8192
#define MAXW 30
#define FFNN 1000
#define FEAT 20

typedef __attribute__((ext_vector_type(8))) short bf16x8;
typedef __attribute__((ext_vector_type(4))) float f32x4;
#define MFMA16 __builtin_amdgcn_mfma_f32_16x16x32_bf16

// ws layout (float-slot offsets)
#define O_P    0                          // 3*1024*1000 fp32 P1,P2,P3
#define O_P4   3072000                    // 30*1000
#define O_HS   3102000                    // 1024
#define O_ATT  3103024                    // 8192*32 (ATT; later SEL/SELKEY/CNT)
#define O_PS   3365168                    // 8192*16 (PS; later MC/ME/MG masks)
#define O_H1R  3504432                    // H1 hi/lo bf16; later pk[8192] u64

__device__ inline ushort f2b(float v) {
    __hip_bfloat16 b = __float2bfloat16(v);
    return *(ushort*)&b;
}
__device__ inline float b2f(ushort u) {
    __hip_bfloat16 b = *(__hip_bfloat16*)&u;
    return __bfloat162float(b);
}

// ---------- head scores ----------
__global__ __launch_bounds__(256) void k_head(const float* __restrict__ doc,
                                              const float* __restrict__ wh,
                                              const float* __restrict__ bh,
                                              float* __restrict__ hs) {
    int wid = threadIdx.x >> 6, lane = threadIdx.x & 63;
    int word = blockIdx.x * 4 + wid;
    const float* row = doc + word * D;
    float acc = 0.f;
    for (int d = lane; d < D; d += 64) acc += row[d] * wh[d];
    #pragma unroll
    for (int o = 32; o; o >>= 1) acc += __shfl_down(acc, o);
    if (lane == 0) hs[word] = acc + bh[0];
}

// ---------- P4 = w_width_emb @ W1[1536:1556,:] ----------
__global__ __launch_bounds__(256) void k_p4(const float* __restrict__ wwe,
                                            const float* __restrict__ W1,
                                            float* __restrict__ P4) {
    int o = blockIdx.x * 256 + threadIdx.x;
    if (o >= 30 * FFNN) return;
    int wi = o / FFNN, j = o - wi * FFNN;
    float acc = 0.f;
    #pragma unroll
    for (int f = 0; f < FEAT; ++f) acc += wwe[wi * FEAT + f] * W1[(1536 + f) * FFNN + j];
    P4[o] = acc;
}

// ---------- split fp32 -> bf16 hi/lo ----------
__global__ __launch_bounds__(256) void k_split(const float* __restrict__ src,
                                               ushort* __restrict__ h,
                                               ushort* __restrict__ l, int n) {
    int i = blockIdx.x * 256 + threadIdx.x;
    if (i >= n) return;
    float v = src[i];
    ushort hi = f2b(v);
    float r = v - b2f(hi);
    h[i] = hi;
    l[i] = f2b(r);
}

// ---------- W1 slices: transpose + split -> W1T[z][1024 n][768 k] hi/lo ----------
__global__ void k_tw1(const float* __restrict__ W1,
                      ushort* __restrict__ TH, ushort* __restrict__ TL) {
    __shared__ float tile[32][33];
    int tx = threadIdx.x, ty = threadIdx.y;
    int k0 = blockIdx.x * 32, n0 = blockIdx.y * 32, z = blockIdx.z;
    int roff = (z == 0) ? 0 : (z == 1) ? 768 : 1556;
    #pragma unroll
    for (int i = 0; i < 4; ++i) {
        int kk = ty + i * 8;
        float v = (n0 + tx < FFNN) ? W1[(size_t)(roff + k0 + kk) * FFNN + n0 + tx] : 0.f;
        tile[kk][tx] = v;
    }
    __syncthreads();
    #pragma unroll
    for (int i = 0; i < 4; ++i) {
        int nn = ty + i * 8;
        float v = tile[tx][nn];
        ushort hi = f2b(v);
        float r = v - b2f(hi);
        size_t o = (size_t)z * 1024 * D + (size_t)(n0 + nn) * D + k0 + tx;
        TH[o] = hi;
        TL[o] = f2b(r);
    }
}

// ---------- W2: transpose + split -> W2T[1024 n][1000 k] hi/lo ----------
__global__ void k_tw2(const float* __restrict__ W2,
                      ushort* __restrict__ TH, ushort* __restrict__ TL) {
    __shared__ float tile[32][33];
    int tx = threadIdx.x, ty = threadIdx.y;
    int k0 = blockIdx.x * 32, n0 = blockIdx.y * 32;
    #pragma unroll
    for (int i = 0; i < 4; ++i) {
        int kk = ty + i * 8;
        float v = (k0 + kk < FFNN && n0 + tx < FFNN)
                    ? W2[(size_t)(k0 + kk) * FFNN + n0 + tx] : 0.f;
        tile[kk][tx] = v;
    }
    __syncthreads();
    #pragma unroll
    for (int i = 0; i < 4; ++i) {
        int nn = ty + i * 8;
        int k = k0 + tx;
        if (k < FFNN) {
            float v = tile[tx][nn];
            ushort hi = f2b(v);
            float r = v - b2f(hi);
            size_t o = (size_t)(n0 + nn) * FFNN + k;
            TH[o] = hi;
            TL[o] = f2b(r);
        }
    }
}

// ---------- MFMA GEMM: P[z] = doc @ W1slice  (split-bf16 3-term, 128x128 tile) ----------
__global__ __launch_bounds__(256) void k_gemmPm(const ushort* __restrict__ Ah_g,
                                                const ushort* __restrict__ Al_g,
                                                const ushort* __restrict__ Bh_g,
                                                const ushort* __restrict__ Bl_g,
                                                float* __restrict__ Pout) {
    __shared__ ushort Ah[128][40], Al[128][40], Bh[128][40], Bl[128][40];
    int tid = threadIdx.x;
    int row0 = blockIdx.y * 128, col0 = blockIdx.x * 128;
    size_t zoff = (size_t)blockIdx.z * 1024 * D;
    const ushort* Bh_z = Bh_g + zoff;
    const ushort* Bl_z = Bl_g + zoff;
    float* C = Pout + (size_t)blockIdx.z * NW * FFNN;
    int w = tid >> 6, l = tid & 63;
    int wr = w >> 1, wc = w & 1;
    int fr = l & 15, kb = l >> 4;
    f32x4 acc[4][4] = {};
    for (int kt = 0; kt < D; kt += 32) {
        #pragma unroll
        for (int i = 0; i < 2; ++i) {
            int cid = tid + i * 256;
            int r = cid >> 2, kc = cid & 3;
            int kg = kt + kc * 8;
            uint4 a0 = *(const uint4*)(Ah_g + (size_t)(row0 + r) * D + kg);
            uint4 a1 = *(const uint4*)(Al_g + (size_t)(row0 + r) * D + kg);
            uint4 b0 = *(const uint4*)(Bh_z + (size_t)(col0 + r) * D + kg);
            uint4 b1 = *(const uint4*)(Bl_z + (size_t)(col0 + r) * D + kg);
            *(uint4*)&Ah[r][kc * 8] = a0;
            *(uint4*)&Al[r][kc * 8] = a1;
            *(uint4*)&Bh[r][kc * 8] = b0;
            *(uint4*)&Bl[r][kc * 8] = b1;
        }
        __syncthreads();
        bf16x8 af[4], alf[4], bfr[4], blf[4];
        #pragma unroll
        for (int mt = 0; mt < 4; ++mt) {
            int r = wr * 64 + mt * 16 + fr;
            af[mt]  = *(const bf16x8*)&Ah[r][kb * 8];
            alf[mt] = *(const bf16x8*)&Al[r][kb * 8];
        }
        #pragma unroll
        for (int nt = 0; nt < 4; ++nt) {
            int c = wc * 64 + nt * 16 + fr;
            bfr[nt] = *(const bf16x8*)&Bh[c][kb * 8];
            blf[nt] = *(const bf16x8*)&Bl[c][kb * 8];
        }
        #pragma unroll
        for (int mt = 0; mt < 4; ++mt)
            #pragma unroll
            for (int nt = 0; nt < 4; ++nt) {
                acc[mt][nt] = MFMA16(af[mt], bfr[nt], acc[mt][nt], 0, 0, 0);
                acc[mt][nt] = MFMA16(af[mt], blf[nt], acc[mt][nt], 0, 0, 0);
                acc[mt][nt] = MFMA16(alf[mt], bfr[nt], acc[mt][nt], 0, 0, 0);
            }
        __syncthreads();
    }
    #pragma unroll
    for (int mt = 0; mt < 4; ++mt)
        #pragma unroll
        for (int nt = 0; nt < 4; ++nt)
            #pragma unroll
            for (int r = 0; r < 4; ++r) {
                int row = row0 + wr * 64 + mt * 16 + kb * 4 + r;
                int col = col0 + wc * 64 + nt * 16 + fr;
                if (col < FFNN) C[(size_t)row * FFNN + col] = acc[mt][nt][r];
            }
}

// ---------- MFMA GEMM2 fused: relu(H1@W2+b2).W3 -> PS  (split-bf16, 128x128) ----------
__global__ __launch_bounds__(256) void k_gemm2m(const ushort* __restrict__ Ah_g,
                                                const ushort* __restrict__ Al_g,
                                                const ushort* __restrict__ Bh_g,
                                                const ushort* __restrict__ Bl_g,
                                                const float* __restrict__ b2,
                                                const float* __restrict__ W3,
                                                float* __restrict__ PS) {
    __shared__ ushort Ah[128][40], Al[128][40], Bh[128][40], Bl[128][40];
    int tid = threadIdx.x;
    int row0 = blockIdx.y * 128, col0 = blockIdx.x * 128;
    int w = tid >> 6, l = tid & 63;
    int wr = w >> 1, wc = w & 1;
    int fr = l & 15, kb = l >> 4;
    f32x4 acc[4][4] = {};
    for (int kt = 0; kt < FFNN; kt += 32) {
        #pragma unroll
        for (int i = 0; i < 2; ++i) {
            int cid = tid + i * 256;
            int r = cid >> 2, kc = cid & 3;
            int kg = kt + kc * 8;
            bool v = (kg + 7) < FFNN;
            uint4 z = make_uint4(0, 0, 0, 0);
            uint4 a0 = v ? *(const uint4*)(Ah_g + (size_t)(row0 + r) * FFNN + kg) : z;
            uint4 a1 = v ? *(const uint4*)(Al_g + (size_t)(row0 + r) * FFNN + kg) : z;
            uint4 b0 = v ? *(const uint4*)(Bh_g + (size_t)(col0 + r) * FFNN + kg) : z;
            uint4 b1 = v ? *(const uint4*)(Bl_g + (size_t)(col0 + r) * FFNN + kg) : z;
            *(uint4*)&Ah[r][kc * 8] = a0;
            *(uint4*)&Al[r][kc * 8] = a1;
            *(uint4*)&Bh[r][kc * 8] = b0;
            *(uint4*)&Bl[r][kc * 8] = b1;
        }
        __syncthreads();
        bf16x8 af[4], alf[4], bfr[4], blf[4];
        #pragma unroll
        for (int mt = 0; mt < 4; ++mt) {
            int r = wr * 64 + mt * 16 + fr;
            af[mt]  = *(const bf16x8*)&Ah[r][kb * 8];
            alf[mt] = *(const bf16x8*)&Al[r][kb * 8];
        }
        #pragma unroll
        for (int nt = 0; nt < 4; ++nt) {
            int c = wc * 64 + nt * 16 + fr;
            bfr[nt] = *(const bf16x8*)&Bh[c][kb * 8];
            blf[nt] = *(const bf16x8*)&Bl[c][kb * 8];
        }
        #pragma unroll
        for (int mt = 0; mt < 4; ++mt)
            #pragma unroll
            for (int nt = 0; nt < 4; ++nt) {
                acc[mt][nt] = MFMA16(af[mt], bfr[nt], acc[mt][nt], 0, 0, 0);
                acc[mt][nt] = MFMA16(af[mt], blf[nt], acc[mt][nt], 0, 0, 0);
                acc[mt][nt] = MFMA16(alf[mt], bfr[nt], acc[mt][nt], 0, 0, 0);
            }
        __syncthreads();
    }
    float w3v[4], b2v[4];
    #pragma unroll
    for (int nt = 0; nt < 4; ++nt) {
        int col = col0 + wc * 64 + nt * 16 + fr;
        bool cv = col < FFNN;
        w3v[nt] = cv ? W3[col] : 0.f;
        b2v[nt] = cv ? b2[col] : 0.f;
    }
    #pragma unroll
    for (int mt = 0; mt < 4; ++mt) {
        #pragma unroll
        for (int r = 0; r < 4; ++r) {
            float p = 0.f;
            #pragma unroll
            for (int nt = 0; nt < 4; ++nt) {
                float v = fmaxf(acc[mt][nt][r] + b2v[nt], 0.f);
                p = fmaf(v, w3v[nt], p);
            }
            p += __shfl_xor(p, 1);
            p += __shfl_xor(p, 2);
            p += __shfl_xor(p, 4);
            p += __shfl_xor(p, 8);
            if (fr == 0) {
                int row = row0 + wr * 64 + mt * 16 + kb * 4 + r;
                PS[row * 16 + blockIdx.x * 2 + wc] = p;
            }
        }
    }
}

// ---------- attention weights per span ----------
__global__ __launch_bounds__(256) void k_attn(const float* __restrict__ hs,
                                              const int* __restrict__ starts,
                                              const int* __restrict__ ends,
                                              float* __restrict__ attn) {
    int s = blockIdx.x * 256 + threadIdx.x;
    if (s >= NS) return;
    int st = starts[s], en = ends[s];
    int width = en - st + 1;
    float v[MAXW];
    float mx = -3.0e38f;
    #pragma unroll
    for (int w = 0; w < MAXW; ++w) {
        int idx = st + w; if (idx > NW - 1) idx = NW - 1;
        float x = hs[idx];
        v[w] = (w < width) ? x : -3.0e38f;
        mx = fmaxf(mx, v[w]);
    }
    float sum = 0.f;
    #pragma unroll
    for (int w = 0; w < MAXW; ++w) { v[w] = expf(v[w] - mx); sum += v[w]; }
    float inv = 1.f / sum;
    #pragma unroll
    for (int w = 0; w < MAXW; ++w) attn[s * 32 + w] = v[w] * inv;
}

// ---------- h1 assembly: gather P rows + attended + bias + relu -> bf16 hi/lo ----------
__global__ __launch_bounds__(256) void k_h1(const float* __restrict__ P,
                                            const float* __restrict__ P4,
                                            const float* __restrict__ attn,
                                            const float* __restrict__ b1,
                                            const int* __restrict__ starts,
                                            const int* __restrict__ ends,
                                            ushort* __restrict__ H1h,
                                            ushort* __restrict__ H1l) {
    int s = blockIdx.x;
    int tid = threadIdx.x;
    if (tid >= 250) return;
    int st = starts[s], en = ends[s];
    int width = en - st + 1;
    const float4* P1r = (const float4*)(P + (size_t)st * FFNN);
    const float4* P2r = (const float4*)(P + (size_t)NW * FFNN + (size_t)en * FFNN);
    const float*  P3  = P + 2 * (size_t)NW * FFNN;
    const float4* P4r = (const float4*)(P4 + (size_t)(width - 1) * FFNN);
    const float4* b1v = (const float4*)b1;
    const float*  ar  = attn + s * 32;
    float4 a = P1r[tid], b = P2r[tid], c = P4r[tid], d = b1v[tid];
    float4 acc = {a.x + b.x + c.x + d.x,
                  a.y + b.y + c.y + d.y,
                  a.z + b.z + c.z + d.z,
                  a.w + b.w + c.w + d.w};
    for (int w = 0; w < width; ++w) {
        float aw = ar[w];
        float4 p3 = ((const float4*)(P3 + (size_t)(st + w) * FFNN))[tid];
        acc.x = fmaf(aw, p3.x, acc.x);
        acc.y = fmaf(aw, p3.y, acc.y);
        acc.z = fmaf(aw, p3.z, acc.z);
        acc.w = fmaf(aw, p3.w, acc.w);
    }
    float rv[4] = {fmaxf(acc.x, 0.f), fmaxf(acc.y, 0.f), fmaxf(acc.z, 0.f), fmaxf(acc.w, 0.f)};
    ushort4 hi, lo;
    ushort* hp = (ushort*)&hi;
    ushort* lp = (ushort*)&lo;
    #pragma unroll
    for (int j = 0; j < 4; ++j) {
        ushort h = f2b(rv[j]);
        float r = rv[j] - b2f(h);
        hp[j] = h;
        lp[j] = f2b(r);
    }
    *(ushort4*)(H1h + (size_t)s * FFNN + tid * 4) = hi;
    *(ushort4*)(H1l + (size_t)s * FFNN + tid * 4) = lo;
}

// ---------- final score: sum 16 partials + b3 ----------
__global__ __launch_bounds__(256) void k_score2(const float* __restrict__ PS,
                                                const float* __restrict__ b3,
                                                float* __restrict__ out) {
    int r = blockIdx.x * 256 + threadIdx.x;
    if (r >= NS) return;
    float s = 0.f;
    #pragma unroll
    for (int b = 0; b < 16; ++b) s += PS[r * 16 + b];
    out[r] = s + b3[0];
}

// ---------- exact descending argsort; emits packed (span,s,e) per rank ----------
__global__ __launch_bounds__(256) void k_rank(const float* __restrict__ scores,
                                              const int* __restrict__ starts,
                                              const int* __restrict__ ends,
                                              unsigned long long* __restrict__ pk) {
    __shared__ unsigned long long tile[256];
    int i = blockIdx.x * 256 + threadIdx.x;
    unsigned u = __float_as_uint(scores[i]);
    unsigned m = (u >> 31) ? ~u : (u | 0x80000000u);
    unsigned long long key = ((unsigned long long)(~m) << 32) | (unsigned)i;
    int rank = 0;
    for (int t = 0; t < NS / 256; ++t) {
        int j = t * 256 + threadIdx.x;
        unsigned uj = __float_as_uint(scores[j]);
        unsigned mj = (uj >> 31) ? ~uj : (uj | 0x80000000u);
        tile[threadIdx.x] = ((unsigned long long)(~mj) << 32) | (unsigned)j;
        __syncthreads();
        #pragma unroll 8
        for (int q = 0; q < 256; ++q) rank += (tile[q] < key);
        __syncthreads();
    }
    int st = starts[i], en = ends[i];
    pk[rank] = ((unsigned long long)(unsigned)i << 32) |
               ((unsigned)st << 16) | (unsigned)en;
}

// ---------- parallel pairwise-mask precompute: one wave per 64-span chunk ----------
__global__ __launch_bounds__(64) void k_masks(const unsigned long long* __restrict__ pk,
                                              unsigned long long* __restrict__ MC,
                                              unsigned long long* __restrict__ ME,
                                              unsigned long long* __restrict__ MG) {
    int lane = threadIdx.x;
    int c = blockIdx.x;
    unsigned long long p = pk[c * 64 + lane];
    int s = (int)((p >> 16) & 0xFFFF);
    int e = (int)(p & 0xFFFF);
    unsigned long long conf = 0, eqm = 0, gtm = 0;
    for (int r = 1; r < 64; ++r) {
        int j = (lane + r) & 63;
        int sj = __shfl(s, j);
        int ej = __shfl(e, j);
        unsigned long long bit = 1ull << j;
        bool cross = ((sj > s) & (sj <= e) & (ej > e)) |
                     ((ej >= s) & (ej < e) & (sj < s));
        if (cross) conf |= bit;
        if (sj == s) { if (ej == e) eqm |= bit; else if (ej > e) gtm |= bit; }
    }
    MC[c * 64 + lane] = conf;
    ME[c * 64 + lane] = eqm;
    MG[c * 64 + lane] = gtm;
}

// ---------- greedy crossing-suppression scan (masks precomputed) ----------
// O(1) global cross check (mxs/mne/mxe) + ballot-round resolution with
// PRELOADED pairwise masks; commit is fully lane-parallel (no pop loop).
__global__ __launch_bounds__(64) void k_scan(const unsigned long long* __restrict__ pk,
                                             const unsigned long long* __restrict__ MC,
                                             const unsigned long long* __restrict__ ME,
                                             const unsigned long long* __restrict__ MG,
                                             int top, int* __restrict__ SEL,
                                             int* __restrict__ SELKEY,
                                             int* __restrict__ CNT) {
    __shared__ int mxs[NW];    // max start among accepted straddling gap p->p+1
    __shared__ int mne[NW];    // min end among accepted with s'' < p <= e''
    __shared__ int mxe[NW];    // max end among accepted starting exactly at p
    int lane = threadIdx.x;
    unsigned long long lower = (1ull << lane) - 1ull;
    for (int p = lane; p < NW; p += 64) { mxs[p] = -1; mne[p] = NW; mxe[p] = -1; }
    __syncthreads();
    int count = 0;
    unsigned long long pc = pk[lane];
    unsigned long long conf = MC[lane], eqm = ME[lane], gtm = MG[lane];
    for (int c = 0; c < NS / 64 && count < top; ++c) {
        unsigned long long pn = 0, cn = 0, en2 = 0, gn = 0;
        if (c + 1 < NS / 64) {                       // prefetch next chunk
            int o = (c + 1) * 64 + lane;
            pn = pk[o]; cn = MC[o]; en2 = ME[o]; gn = MG[o];
        }
        int span = (int)(pc >> 32);
        int s = (int)((pc >> 16) & 0xFFFF);
        int e = (int)(pc & 0xFFFF);
        int bad = (mxs[e] > s) | (mne[s] < e);       // exact global cross check
        int g = mxe[s];
        bool gdup = (g == e), ggt = (g > e);
        unsigned long long pending = __ballot(!bad), committed = 0;
        unsigned long long relv = (conf | eqm | gtm) & lower;
        while (pending) {
            bool mine = (pending >> lane) & 1;
            bool ready = mine && ((pending & relv) == 0ull);
            unsigned long long cb = committed & lower;
            bool rej = (cb & conf) != 0ull;
            bool gt_any = ggt || ((cb & gtm) != 0ull);
            bool eq_any = gdup || ((cb & eqm) != 0ull);
            bool acc_now = ready && !rej && !(eq_any && !gt_any);
            committed |= __ballot(acc_now);
            pending &= ~__ballot(ready);
        }
        int allowed = top - count;                   // cap at top
        while (__popcll(committed) > allowed)
            committed &= ~(1ull << (63 - __builtin_clzll(committed)));
        if ((committed >> lane) & 1) {               // lane-parallel commit
            int pos = count + __popcll(committed & lower);
            SEL[pos] = span;
            SELKEY[pos] = s * NW + e;
            atomicMax(&mxe[s], e);
            #pragma unroll
            for (int k = 0; k < MAXW - 1; ++k) {
                if (k < e - s) {
                    atomicMax(&mxs[s + k], s);
                    atomicMin(&mne[s + 1 + k], e);
                }
            }
        }
        count += __popcll(committed);
        __syncthreads();
        pc = pn; conf = cn; eqm = en2; gtm = gn;
    }
    if (lane == 0) *CNT = count;
}

// ---------- final sort: multi-wave rank sort of the selected spans ----------
__global__ __launch_bounds__(512) void k_sort(const int* __restrict__ SEL,
                                              const int* __restrict__ SELKEY,
                                              const int* __restrict__ CNT,
                                              int top, float* __restrict__ out_idx) {
    __shared__ int keys[512];
    __shared__ int vals[512];
    int cnt = *CNT;
    int r = threadIdx.x;
    if (r < top) {
        keys[r] = (r < cnt) ? SELKEY[r] : NW * NW;
        vals[r] = (r < cnt) ? SEL[r] : -1;
    }
    __syncthreads();
    if (r < top) {
        int kr = keys[r];
        int rank = 0;
        for (int q = 0; q < top; ++q) {
            int kq = keys[q];
            rank += (kq < kr) || (kq == kr && q < r);
        }
        out_idx[rank] = (float)vals[r];
    }
}

extern "C" void kernel_launch(void* const* d_in, const int* in_sizes, int n_in,
                              void* d_out, int out_size, void* d_ws, size_t ws_size,
                              hipStream_t stream) {
    const float* doc = (const float*)d_in[0];
    const float* wwe = (const float*)d_in[1];
    const float* wh  = (const float*)d_in[2];
    const float* bh  = (const float*)d_in[3];
    const float* W1  = (const float*)d_in[4];
    const float* b1  = (const float*)d_in[5];
    const float* W2  = (const float*)d_in[6];
    const float* b2  = (const float*)d_in[7];
    const float* W3  = (const float*)d_in[8];
    const float* b3  = (const float*)d_in[9];
    const int* starts = (const int*)d_in[10];
    const int* ends   = (const int*)d_in[11];
    int top = out_size - NS;                 // 409

    float* ws  = (float*)d_ws;
    float* P   = ws + O_P;
    float* P4  = ws + O_P4;
    float* HS  = ws + O_HS;
    float* ATT = ws + O_ATT;
    float* PS  = ws + O_PS;
    float* H1R = ws + O_H1R;
    ushort* H1H = (ushort*)H1R;
    ushort* H1L = (ushort*)(H1R + 4096000);
    ushort* W1TH = (ushort*)H1R;
    ushort* W1TL = (ushort*)(H1R + 1179648);
    ushort* DOCH = (ushort*)(H1R + 2359296);
    ushort* DOCL = (ushort*)(H1R + 2752512);
    ushort* W2TH = (ushort*)ws;
    ushort* W2TL = (ushort*)(ws + 512000);
    unsigned long long* PK = (unsigned long long*)H1R;   // dead after k_gemm2m
    int* SEL    = (int*)(ws + O_ATT);                    // ATT dead after k_h1
    int* SELKEY = SEL + 512;
    int* CNT    = SEL + 1024;
    unsigned long long* MC = (unsigned long long*)(ws + O_PS);   // PS dead after k_score2
    unsigned long long* ME = MC + NS;
    unsigned long long* MG = MC + 2 * NS;
    float* outs = (float*)d_out;

    k_head<<<NW / 4, 256, 0, stream>>>(doc, wh, bh, HS);
    k_p4<<<(30 * FFNN + 255) / 256, 256, 0, stream>>>(wwe, W1, P4);

    k_split<<<(NW * D + 255) / 256, 256, 0, stream>>>(doc, DOCH, DOCL, NW * D);
    {
        dim3 g(24, 32, 3), b(32, 8);
        k_tw1<<<g, b, 0, stream>>>(W1, W1TH, W1TL);
    }
    {
        dim3 g(8, 8, 3);
        k_gemmPm<<<g, 256, 0, stream>>>(DOCH, DOCL, W1TH, W1TL, P);
    }

    k_attn<<<NS / 256, 256, 0, stream>>>(HS, starts, ends, ATT);
    k_h1<<<NS, 256, 0, stream>>>(P, P4, ATT, b1, starts, ends, H1H, H1L);

    {
        dim3 g(32, 32), b(32, 8);
        k_tw2<<<g, b, 0, stream>>>(W2, W2TH, W2TL);
    }
    {
        dim3 g(8, NS / 128);
        k_gemm2m<<<g, 256, 0, stream>>>(H1H, H1L, W2TH, W2TL, b2, W3, PS);
    }

    k_score2<<<NS / 256, 256, 0, stream>>>(PS, b3, outs);
    k_rank<<<NS / 256, 256, 0, stream>>>(outs, starts, ends, PK);
    k_masks<<<NS / 64, 64, 0, stream>>>(PK, MC, ME, MG);
    k_scan<<<1, 64, 0, stream>>>(PK, MC, ME, MG, top, SEL, SELKEY, CNT);
    k_sort<<<1, 512, 0, stream>>>(SEL, SELKEY, CNT, top, outs + NS);
}

// Round 10
// 279.868 us; speedup vs baseline: 2.0417x; 1.3952x over previous
//
#include <hip/hip_runtime.h>
#include <hip/hip_bf16.h>
#include <stdint.h>

#define NW   1024
#define D    768
#define NS   8192
#define MAXW 30
#define FFNN 1000
#define FEAT 20

typedef __attribute__((ext_vector_type(8))) short bf16x8;
typedef __attribute__((ext_vector_type(4))) float f32x4;
#define MFMA16 __builtin_amdgcn_mfma_f32_16x16x32_bf16

// ws layout (float-slot offsets)
#define O_P    0                          // 3*1024*1000 fp32 P1,P2,P3
#define O_P4   3072000                    // 30*1000
#define O_HS   3102000                    // 1024
#define O_ATT  3103024                    // 8192*32 (ATT; later SEL/SELKEY/CNT/RANK)
#define O_PS   3365168                    // 8192*16 (PS; later MC/ME/MG masks)
#define O_H1R  3504432                    // H1 hi/lo bf16; later pk[8192] u64

__device__ inline ushort f2b(float v) {
    __hip_bfloat16 b = __float2bfloat16(v);
    return *(ushort*)&b;
}
__device__ inline float b2f(ushort u) {
    __hip_bfloat16 b = *(__hip_bfloat16*)&u;
    return __bfloat162float(b);
}

// ---------- head scores ----------
__global__ __launch_bounds__(256) void k_head(const float* __restrict__ doc,
                                              const float* __restrict__ wh,
                                              const float* __restrict__ bh,
                                              float* __restrict__ hs) {
    int wid = threadIdx.x >> 6, lane = threadIdx.x & 63;
    int word = blockIdx.x * 4 + wid;
    const float* row = doc + word * D;
    float acc = 0.f;
    for (int d = lane; d < D; d += 64) acc += row[d] * wh[d];
    #pragma unroll
    for (int o = 32; o; o >>= 1) acc += __shfl_down(acc, o);
    if (lane == 0) hs[word] = acc + bh[0];
}

// ---------- P4 = w_width_emb @ W1[1536:1556,:] ----------
__global__ __launch_bounds__(256) void k_p4(const float* __restrict__ wwe,
                                            const float* __restrict__ W1,
                                            float* __restrict__ P4) {
    int o = blockIdx.x * 256 + threadIdx.x;
    if (o >= 30 * FFNN) return;
    int wi = o / FFNN, j = o - wi * FFNN;
    float acc = 0.f;
    #pragma unroll
    for (int f = 0; f < FEAT; ++f) acc += wwe[wi * FEAT + f] * W1[(1536 + f) * FFNN + j];
    P4[o] = acc;
}

// ---------- split fp32 -> bf16 hi/lo ----------
__global__ __launch_bounds__(256) void k_split(const float* __restrict__ src,
                                               ushort* __restrict__ h,
                                               ushort* __restrict__ l, int n) {
    int i = blockIdx.x * 256 + threadIdx.x;
    if (i >= n) return;
    float v = src[i];
    ushort hi = f2b(v);
    float r = v - b2f(hi);
    h[i] = hi;
    l[i] = f2b(r);
}

// ---------- W1 slices: transpose + split -> W1T[z][1024 n][768 k] hi/lo ----------
__global__ void k_tw1(const float* __restrict__ W1,
                      ushort* __restrict__ TH, ushort* __restrict__ TL) {
    __shared__ float tile[32][33];
    int tx = threadIdx.x, ty = threadIdx.y;
    int k0 = blockIdx.x * 32, n0 = blockIdx.y * 32, z = blockIdx.z;
    int roff = (z == 0) ? 0 : (z == 1) ? 768 : 1556;
    #pragma unroll
    for (int i = 0; i < 4; ++i) {
        int kk = ty + i * 8;
        float v = (n0 + tx < FFNN) ? W1[(size_t)(roff + k0 + kk) * FFNN + n0 + tx] : 0.f;
        tile[kk][tx] = v;
    }
    __syncthreads();
    #pragma unroll
    for (int i = 0; i < 4; ++i) {
        int nn = ty + i * 8;
        float v = tile[tx][nn];
        ushort hi = f2b(v);
        float r = v - b2f(hi);
        size_t o = (size_t)z * 1024 * D + (size_t)(n0 + nn) * D + k0 + tx;
        TH[o] = hi;
        TL[o] = f2b(r);
    }
}

// ---------- W2: transpose + split -> W2T[1024 n][1000 k] hi/lo ----------
__global__ void k_tw2(const float* __restrict__ W2,
                      ushort* __restrict__ TH, ushort* __restrict__ TL) {
    __shared__ float tile[32][33];
    int tx = threadIdx.x, ty = threadIdx.y;
    int k0 = blockIdx.x * 32, n0 = blockIdx.y * 32;
    #pragma unroll
    for (int i = 0; i < 4; ++i) {
        int kk = ty + i * 8;
        float v = (k0 + kk < FFNN && n0 + tx < FFNN)
                    ? W2[(size_t)(k0 + kk) * FFNN + n0 + tx] : 0.f;
        tile[kk][tx] = v;
    }
    __syncthreads();
    #pragma unroll
    for (int i = 0; i < 4; ++i) {
        int nn = ty + i * 8;
        int k = k0 + tx;
        if (k < FFNN) {
            float v = tile[tx][nn];
            ushort hi = f2b(v);
            float r = v - b2f(hi);
            size_t o = (size_t)(n0 + nn) * FFNN + k;
            TH[o] = hi;
            TL[o] = f2b(r);
        }
    }
}

// ---------- MFMA GEMM: P[z] = doc @ W1slice  (split-bf16 3-term, 128x128 tile) ----------
__global__ __launch_bounds__(256) void k_gemmPm(const ushort* __restrict__ Ah_g,
                                                const ushort* __restrict__ Al_g,
                                                const ushort* __restrict__ Bh_g,
                                                const ushort* __restrict__ Bl_g,
                                                float* __restrict__ Pout) {
    __shared__ ushort Ah[128][40], Al[128][40], Bh[128][40], Bl[128][40];
    int tid = threadIdx.x;
    int row0 = blockIdx.y * 128, col0 = blockIdx.x * 128;
    size_t zoff = (size_t)blockIdx.z * 1024 * D;
    const ushort* Bh_z = Bh_g + zoff;
    const ushort* Bl_z = Bl_g + zoff;
    float* C = Pout + (size_t)blockIdx.z * NW * FFNN;
    int w = tid >> 6, l = tid & 63;
    int wr = w >> 1, wc = w & 1;
    int fr = l & 15, kb = l >> 4;
    f32x4 acc[4][4] = {};
    for (int kt = 0; kt < D; kt += 32) {
        #pragma unroll
        for (int i = 0; i < 2; ++i) {
            int cid = tid + i * 256;
            int r = cid >> 2, kc = cid & 3;
            int kg = kt + kc * 8;
            uint4 a0 = *(const uint4*)(Ah_g + (size_t)(row0 + r) * D + kg);
            uint4 a1 = *(const uint4*)(Al_g + (size_t)(row0 + r) * D + kg);
            uint4 b0 = *(const uint4*)(Bh_z + (size_t)(col0 + r) * D + kg);
            uint4 b1 = *(const uint4*)(Bl_z + (size_t)(col0 + r) * D + kg);
            *(uint4*)&Ah[r][kc * 8] = a0;
            *(uint4*)&Al[r][kc * 8] = a1;
            *(uint4*)&Bh[r][kc * 8] = b0;
            *(uint4*)&Bl[r][kc * 8] = b1;
        }
        __syncthreads();
        bf16x8 af[4], alf[4], bfr[4], blf[4];
        #pragma unroll
        for (int mt = 0; mt < 4; ++mt) {
            int r = wr * 64 + mt * 16 + fr;
            af[mt]  = *(const bf16x8*)&Ah[r][kb * 8];
            alf[mt] = *(const bf16x8*)&Al[r][kb * 8];
        }
        #pragma unroll
        for (int nt = 0; nt < 4; ++nt) {
            int c = wc * 64 + nt * 16 + fr;
            bfr[nt] = *(const bf16x8*)&Bh[c][kb * 8];
            blf[nt] = *(const bf16x8*)&Bl[c][kb * 8];
        }
        #pragma unroll
        for (int mt = 0; mt < 4; ++mt)
            #pragma unroll
            for (int nt = 0; nt < 4; ++nt) {
                acc[mt][nt] = MFMA16(af[mt], bfr[nt], acc[mt][nt], 0, 0, 0);
                acc[mt][nt] = MFMA16(af[mt], blf[nt], acc[mt][nt], 0, 0, 0);
                acc[mt][nt] = MFMA16(alf[mt], bfr[nt], acc[mt][nt], 0, 0, 0);
            }
        __syncthreads();
    }
    #pragma unroll
    for (int mt = 0; mt < 4; ++mt)
        #pragma unroll
        for (int nt = 0; nt < 4; ++nt)
            #pragma unroll
            for (int r = 0; r < 4; ++r) {
                int row = row0 + wr * 64 + mt * 16 + kb * 4 + r;
                int col = col0 + wc * 64 + nt * 16 + fr;
                if (col < FFNN) C[(size_t)row * FFNN + col] = acc[mt][nt][r];
            }
}

// ---------- MFMA GEMM2 fused: relu(H1@W2+b2).W3 -> PS  (split-bf16, 128x128) ----------
__global__ __launch_bounds__(256) void k_gemm2m(const ushort* __restrict__ Ah_g,
                                                const ushort* __restrict__ Al_g,
                                                const ushort* __restrict__ Bh_g,
                                                const ushort* __restrict__ Bl_g,
                                                const float* __restrict__ b2,
                                                const float* __restrict__ W3,
                                                float* __restrict__ PS) {
    __shared__ ushort Ah[128][40], Al[128][40], Bh[128][40], Bl[128][40];
    int tid = threadIdx.x;
    int row0 = blockIdx.y * 128, col0 = blockIdx.x * 128;
    int w = tid >> 6, l = tid & 63;
    int wr = w >> 1, wc = w & 1;
    int fr = l & 15, kb = l >> 4;
    f32x4 acc[4][4] = {};
    for (int kt = 0; kt < FFNN; kt += 32) {
        #pragma unroll
        for (int i = 0; i < 2; ++i) {
            int cid = tid + i * 256;
            int r = cid >> 2, kc = cid & 3;
            int kg = kt + kc * 8;
            bool v = (kg + 7) < FFNN;
            uint4 z = make_uint4(0, 0, 0, 0);
            uint4 a0 = v ? *(const uint4*)(Ah_g + (size_t)(row0 + r) * FFNN + kg) : z;
            uint4 a1 = v ? *(const uint4*)(Al_g + (size_t)(row0 + r) * FFNN + kg) : z;
            uint4 b0 = v ? *(const uint4*)(Bh_g + (size_t)(col0 + r) * FFNN + kg) : z;
            uint4 b1 = v ? *(const uint4*)(Bl_g + (size_t)(col0 + r) * FFNN + kg) : z;
            *(uint4*)&Ah[r][kc * 8] = a0;
            *(uint4*)&Al[r][kc * 8] = a1;
            *(uint4*)&Bh[r][kc * 8] = b0;
            *(uint4*)&Bl[r][kc * 8] = b1;
        }
        __syncthreads();
        bf16x8 af[4], alf[4], bfr[4], blf[4];
        #pragma unroll
        for (int mt = 0; mt < 4; ++mt) {
            int r = wr * 64 + mt * 16 + fr;
            af[mt]  = *(const bf16x8*)&Ah[r][kb * 8];
            alf[mt] = *(const bf16x8*)&Al[r][kb * 8];
        }
        #pragma unroll
        for (int nt = 0; nt < 4; ++nt) {
            int c = wc * 64 + nt * 16 + fr;
            bfr[nt] = *(const bf16x8*)&Bh[c][kb * 8];
            blf[nt] = *(const bf16x8*)&Bl[c][kb * 8];
        }
        #pragma unroll
        for (int mt = 0; mt < 4; ++mt)
            #pragma unroll
            for (int nt = 0; nt < 4; ++nt) {
                acc[mt][nt] = MFMA16(af[mt], bfr[nt], acc[mt][nt], 0, 0, 0);
                acc[mt][nt] = MFMA16(af[mt], blf[nt], acc[mt][nt], 0, 0, 0);
                acc[mt][nt] = MFMA16(alf[mt], bfr[nt], acc[mt][nt], 0, 0, 0);
            }
        __syncthreads();
    }
    float w3v[4], b2v[4];
    #pragma unroll
    for (int nt = 0; nt < 4; ++nt) {
        int col = col0 + wc * 64 + nt * 16 + fr;
        bool cv = col < FFNN;
        w3v[nt] = cv ? W3[col] : 0.f;
        b2v[nt] = cv ? b2[col] : 0.f;
    }
    #pragma unroll
    for (int mt = 0; mt < 4; ++mt) {
        #pragma unroll
        for (int r = 0; r < 4; ++r) {
            float p = 0.f;
            #pragma unroll
            for (int nt = 0; nt < 4; ++nt) {
                float v = fmaxf(acc[mt][nt][r] + b2v[nt], 0.f);
                p = fmaf(v, w3v[nt], p);
            }
            p += __shfl_xor(p, 1);
            p += __shfl_xor(p, 2);
            p += __shfl_xor(p, 4);
            p += __shfl_xor(p, 8);
            if (fr == 0) {
                int row = row0 + wr * 64 + mt * 16 + kb * 4 + r;
                PS[row * 16 + blockIdx.x * 2 + wc] = p;
            }
        }
    }
}

// ---------- attention weights per span ----------
__global__ __launch_bounds__(256) void k_attn(const float* __restrict__ hs,
                                              const int* __restrict__ starts,
                                              const int* __restrict__ ends,
                                              float* __restrict__ attn) {
    int s = blockIdx.x * 256 + threadIdx.x;
    if (s >= NS) return;
    int st = starts[s], en = ends[s];
    int width = en - st + 1;
    float v[MAXW];
    float mx = -3.0e38f;
    #pragma unroll
    for (int w = 0; w < MAXW; ++w) {
        int idx = st + w; if (idx > NW - 1) idx = NW - 1;
        float x = hs[idx];
        v[w] = (w < width) ? x : -3.0e38f;
        mx = fmaxf(mx, v[w]);
    }
    float sum = 0.f;
    #pragma unroll
    for (int w = 0; w < MAXW; ++w) { v[w] = expf(v[w] - mx); sum += v[w]; }
    float inv = 1.f / sum;
    #pragma unroll
    for (int w = 0; w < MAXW; ++w) attn[s * 32 + w] = v[w] * inv;
}

// ---------- h1 assembly: gather P rows + attended + bias + relu -> bf16 hi/lo ----------
__global__ __launch_bounds__(256) void k_h1(const float* __restrict__ P,
                                            const float* __restrict__ P4,
                                            const float* __restrict__ attn,
                                            const float* __restrict__ b1,
                                            const int* __restrict__ starts,
                                            const int* __restrict__ ends,
                                            ushort* __restrict__ H1h,
                                            ushort* __restrict__ H1l) {
    int s = blockIdx.x;
    int tid = threadIdx.x;
    if (tid >= 250) return;
    int st = starts[s], en = ends[s];
    int width = en - st + 1;
    const float4* P1r = (const float4*)(P + (size_t)st * FFNN);
    const float4* P2r = (const float4*)(P + (size_t)NW * FFNN + (size_t)en * FFNN);
    const float*  P3  = P + 2 * (size_t)NW * FFNN;
    const float4* P4r = (const float4*)(P4 + (size_t)(width - 1) * FFNN);
    const float4* b1v = (const float4*)b1;
    const float*  ar  = attn + s * 32;
    float4 a = P1r[tid], b = P2r[tid], c = P4r[tid], d = b1v[tid];
    float4 acc = {a.x + b.x + c.x + d.x,
                  a.y + b.y + c.y + d.y,
                  a.z + b.z + c.z + d.z,
                  a.w + b.w + c.w + d.w};
    for (int w = 0; w < width; ++w) {
        float aw = ar[w];
        float4 p3 = ((const float4*)(P3 + (size_t)(st + w) * FFNN))[tid];
        acc.x = fmaf(aw, p3.x, acc.x);
        acc.y = fmaf(aw, p3.y, acc.y);
        acc.z = fmaf(aw, p3.z, acc.z);
        acc.w = fmaf(aw, p3.w, acc.w);
    }
    float rv[4] = {fmaxf(acc.x, 0.f), fmaxf(acc.y, 0.f), fmaxf(acc.z, 0.f), fmaxf(acc.w, 0.f)};
    ushort4 hi, lo;
    ushort* hp = (ushort*)&hi;
    ushort* lp = (ushort*)&lo;
    #pragma unroll
    for (int j = 0; j < 4; ++j) {
        ushort h = f2b(rv[j]);
        float r = rv[j] - b2f(h);
        hp[j] = h;
        lp[j] = f2b(r);
    }
    *(ushort4*)(H1h + (size_t)s * FFNN + tid * 4) = hi;
    *(ushort4*)(H1l + (size_t)s * FFNN + tid * 4) = lo;
}

// ---------- final score: sum 16 partials + b3 ----------
__global__ __launch_bounds__(256) void k_score2(const float* __restrict__ PS,
                                                const float* __restrict__ b3,
                                                float* __restrict__ out) {
    int r = blockIdx.x * 256 + threadIdx.x;
    if (r >= NS) return;
    float s = 0.f;
    #pragma unroll
    for (int b = 0; b < 16; ++b) s += PS[r * 16 + b];
    out[r] = s + b3[0];
}

// ---------- tile-parallel rank: RANK[i] += #{j in tile bj : key[j] < key[i]} ----------
__global__ __launch_bounds__(256) void k_rankA(const float* __restrict__ scores,
                                               int* __restrict__ RANK) {
    __shared__ unsigned long long tile[256];
    int i = blockIdx.x * 256 + threadIdx.x;
    int j = blockIdx.y * 256 + threadIdx.x;
    unsigned uj = __float_as_uint(scores[j]);
    unsigned mj = (uj >> 31) ? ~uj : (uj | 0x80000000u);
    tile[threadIdx.x] = ((unsigned long long)(~mj) << 32) | (unsigned)j;
    __syncthreads();
    unsigned u = __float_as_uint(scores[i]);
    unsigned m = (u >> 31) ? ~u : (u | 0x80000000u);
    unsigned long long key = ((unsigned long long)(~m) << 32) | (unsigned)i;
    int r = 0;
    #pragma unroll 8
    for (int q = 0; q < 256; ++q) r += (tile[q] < key);
    if (r) atomicAdd(&RANK[i], r);
}

// ---------- scatter: pk[RANK[i]] = packed (span, start, end) ----------
__global__ __launch_bounds__(256) void k_rankB(const int* __restrict__ RANK,
                                               const int* __restrict__ starts,
                                               const int* __restrict__ ends,
                                               unsigned long long* __restrict__ pk) {
    int i = blockIdx.x * 256 + threadIdx.x;
    pk[RANK[i]] = ((unsigned long long)(unsigned)i << 32) |
                  ((unsigned)starts[i] << 16) | (unsigned)ends[i];
}

// ---------- parallel pairwise-mask precompute: one wave per 64-span chunk ----------
__global__ __launch_bounds__(64) void k_masks(const unsigned long long* __restrict__ pk,
                                              unsigned long long* __restrict__ MC,
                                              unsigned long long* __restrict__ ME,
                                              unsigned long long* __restrict__ MG) {
    int lane = threadIdx.x;
    int c = blockIdx.x;
    unsigned long long p = pk[c * 64 + lane];
    int s = (int)((p >> 16) & 0xFFFF);
    int e = (int)(p & 0xFFFF);
    unsigned long long conf = 0, eqm = 0, gtm = 0;
    for (int r = 1; r < 64; ++r) {
        int j = (lane + r) & 63;
        int sj = __shfl(s, j);
        int ej = __shfl(e, j);
        unsigned long long bit = 1ull << j;
        bool cross = ((sj > s) & (sj <= e) & (ej > e)) |
                     ((ej >= s) & (ej < e) & (sj < s));
        if (cross) conf |= bit;
        if (sj == s) { if (ej == e) eqm |= bit; else if (ej > e) gtm |= bit; }
    }
    MC[c * 64 + lane] = conf;
    ME[c * 64 + lane] = eqm;
    MG[c * 64 + lane] = gtm;
}

// ---------- greedy crossing-suppression scan (masks precomputed) ----------
__global__ __launch_bounds__(64) void k_scan(const unsigned long long* __restrict__ pk,
                                             const unsigned long long* __restrict__ MC,
                                             const unsigned long long* __restrict__ ME,
                                             const unsigned long long* __restrict__ MG,
                                             int top, int* __restrict__ SEL,
                                             int* __restrict__ SELKEY,
                                             int* __restrict__ CNT) {
    __shared__ int mxs[NW];
    __shared__ int mne[NW];
    __shared__ int mxe[NW];
    int lane = threadIdx.x;
    unsigned long long lower = (1ull << lane) - 1ull;
    for (int p = lane; p < NW; p += 64) { mxs[p] = -1; mne[p] = NW; mxe[p] = -1; }
    __syncthreads();
    int count = 0;
    unsigned long long pc = pk[lane];
    unsigned long long conf = MC[lane], eqm = ME[lane], gtm = MG[lane];
    for (int c = 0; c < NS / 64 && count < top; ++c) {
        unsigned long long pn = 0, cn = 0, en2 = 0, gn = 0;
        if (c + 1 < NS / 64) {
            int o = (c + 1) * 64 + lane;
            pn = pk[o]; cn = MC[o]; en2 = ME[o]; gn = MG[o];
        }
        int span = (int)(pc >> 32);
        int s = (int)((pc >> 16) & 0xFFFF);
        int e = (int)(pc & 0xFFFF);
        int bad = (mxs[e] > s) | (mne[s] < e);
        int g = mxe[s];
        bool gdup = (g == e), ggt = (g > e);
        unsigned long long pending = __ballot(!bad), committed = 0;
        unsigned long long relv = (conf | eqm | gtm) & lower;
        while (pending) {
            bool mine = (pending >> lane) & 1;
            bool ready = mine && ((pending & relv) == 0ull);
            unsigned long long cb = committed & lower;
            bool rej = (cb & conf) != 0ull;
            bool gt_any = ggt || ((cb & gtm) != 0ull);
            bool eq_any = gdup || ((cb & eqm) != 0ull);
            bool acc_now = ready && !rej && !(eq_any && !gt_any);
            committed |= __ballot(acc_now);
            pending &= ~__ballot(ready);
        }
        int allowed = top - count;
        while (__popcll(committed) > allowed)
            committed &= ~(1ull << (63 - __builtin_clzll(committed)));
        if ((committed >> lane) & 1) {
            int pos = count + __popcll(committed & lower);
            SEL[pos] = span;
            SELKEY[pos] = s * NW + e;
            atomicMax(&mxe[s], e);
            #pragma unroll
            for (int k = 0; k < MAXW - 1; ++k) {
                if (k < e - s) {
                    atomicMax(&mxs[s + k], s);
                    atomicMin(&mne[s + 1 + k], e);
                }
            }
        }
        count += __popcll(committed);
        __syncthreads();
        pc = pn; conf = cn; eqm = en2; gtm = gn;
    }
    if (lane == 0) *CNT = count;
}

// ---------- final sort: multi-wave rank sort of the selected spans ----------
__global__ __launch_bounds__(512) void k_sort(const int* __restrict__ SEL,
                                              const int* __restrict__ SELKEY,
                                              const int* __restrict__ CNT,
                                              int top, float* __restrict__ out_idx) {
    __shared__ int keys[512];
    __shared__ int vals[512];
    int cnt = *CNT;
    int r = threadIdx.x;
    if (r < top) {
        keys[r] = (r < cnt) ? SELKEY[r] : NW * NW;
        vals[r] = (r < cnt) ? SEL[r] : -1;
    }
    __syncthreads();
    if (r < top) {
        int kr = keys[r];
        int rank = 0;
        for (int q = 0; q < top; ++q) {
            int kq = keys[q];
            rank += (kq < kr) || (kq == kr && q < r);
        }
        out_idx[rank] = (float)vals[r];
    }
}

extern "C" void kernel_launch(void* const* d_in, const int* in_sizes, int n_in,
                              void* d_out, int out_size, void* d_ws, size_t ws_size,
                              hipStream_t stream) {
    const float* doc = (const float*)d_in[0];
    const float* wwe = (const float*)d_in[1];
    const float* wh  = (const float*)d_in[2];
    const float* bh  = (const float*)d_in[3];
    const float* W1  = (const float*)d_in[4];
    const float* b1  = (const float*)d_in[5];
    const float* W2  = (const float*)d_in[6];
    const float* b2  = (const float*)d_in[7];
    const float* W3  = (const float*)d_in[8];
    const float* b3  = (const float*)d_in[9];
    const int* starts = (const int*)d_in[10];
    const int* ends   = (const int*)d_in[11];
    int top = out_size - NS;                 // 409

    float* ws  = (float*)d_ws;
    float* P   = ws + O_P;
    float* P4  = ws + O_P4;
    float* HS  = ws + O_HS;
    float* ATT = ws + O_ATT;
    float* PS  = ws + O_PS;
    float* H1R = ws + O_H1R;
    ushort* H1H = (ushort*)H1R;
    ushort* H1L = (ushort*)(H1R + 4096000);
    ushort* W1TH = (ushort*)H1R;
    ushort* W1TL = (ushort*)(H1R + 1179648);
    ushort* DOCH = (ushort*)(H1R + 2359296);
    ushort* DOCL = (ushort*)(H1R + 2752512);
    ushort* W2TH = (ushort*)ws;
    ushort* W2TL = (ushort*)(ws + 512000);
    unsigned long long* PK = (unsigned long long*)H1R;   // dead after k_gemm2m
    int* SEL    = (int*)(ws + O_ATT);                    // ATT dead after k_h1
    int* SELKEY = SEL + 512;
    int* CNT    = SEL + 1024;
    int* RANK   = SEL + 2048;                            // 8192 ints
    unsigned long long* MC = (unsigned long long*)(ws + O_PS);   // PS dead after k_score2
    unsigned long long* ME = MC + NS;
    unsigned long long* MG = MC + 2 * NS;
    float* outs = (float*)d_out;

    k_head<<<NW / 4, 256, 0, stream>>>(doc, wh, bh, HS);
    k_p4<<<(30 * FFNN + 255) / 256, 256, 0, stream>>>(wwe, W1, P4);

    k_split<<<(NW * D + 255) / 256, 256, 0, stream>>>(doc, DOCH, DOCL, NW * D);
    {
        dim3 g(24, 32, 3), b(32, 8);
        k_tw1<<<g, b, 0, stream>>>(W1, W1TH, W1TL);
    }
    {
        dim3 g(8, 8, 3);
        k_gemmPm<<<g, 256, 0, stream>>>(DOCH, DOCL, W1TH, W1TL, P);
    }

    k_attn<<<NS / 256, 256, 0, stream>>>(HS, starts, ends, ATT);
    k_h1<<<NS, 256, 0, stream>>>(P, P4, ATT, b1, starts, ends, H1H, H1L);

    {
        dim3 g(32, 32), b(32, 8);
        k_tw2<<<g, b, 0, stream>>>(W2, W2TH, W2TL);
    }
    {
        dim3 g(8, NS / 128);
        k_gemm2m<<<g, 256, 0, stream>>>(H1H, H1L, W2TH, W2TL, b2, W3, PS);
    }

    k_score2<<<NS / 256, 256, 0, stream>>>(PS, b3, outs);

    hipMemsetAsync(RANK, 0, NS * sizeof(int), stream);
    {
        dim3 g(NS / 256, NS / 256);
        k_rankA<<<g, 256, 0, stream>>>(outs, RANK);
    }
    k_rankB<<<NS / 256, 256, 0, stream>>>(RANK, starts, ends, PK);
    k_masks<<<NS / 64, 64, 0, stream>>>(PK, MC, ME, MG);
    k_scan<<<1, 64, 0, stream>>>(PK, MC, ME, MG, top, SEL, SELKEY, CNT);
    k_sort<<<1, 512, 0, stream>>>(SEL, SELKEY, CNT, top, outs + NS);
}

// Round 11
// 267.619 us; speedup vs baseline: 2.1352x; 1.0458x over previous
//
#include <hip/hip_runtime.h>
#include <hip/hip_bf16.h>
#include <stdint.h>

#define NW   1024
#define D    768
#define NS   8192
#define MAXW 30
#define FFNN 1000
#define FEAT 20

typedef __attribute__((ext_vector_type(8))) short bf16x8;
typedef __attribute__((ext_vector_type(4))) float f32x4;
#define MFMA16 __builtin_amdgcn_mfma_f32_16x16x32_bf16

// ws layout (float-slot offsets)
#define O_P    0                          // 3*1024*1000 fp32 P1,P2,P3
#define O_P4   3072000                    // 30*1000
#define O_HS   3102000                    // 1024
#define O_ATT  3103024                    // 8192*32 (ATT; later SEL/SELKEY/CNT/RANK)
#define O_PS   3365168                    // 8192*16 (PS; later MC/ME/MG masks)
#define O_H1R  3504432                    // H1 hi/lo bf16; later pk[8192] u64

__device__ inline ushort f2b(float v) {
    __hip_bfloat16 b = __float2bfloat16(v);
    return *(ushort*)&b;
}
__device__ inline float b2f(ushort u) {
    __hip_bfloat16 b = *(__hip_bfloat16*)&u;
    return __bfloat162float(b);
}

// ---------- head scores ----------
__global__ __launch_bounds__(256) void k_head(const float* __restrict__ doc,
                                              const float* __restrict__ wh,
                                              const float* __restrict__ bh,
                                              float* __restrict__ hs) {
    int wid = threadIdx.x >> 6, lane = threadIdx.x & 63;
    int word = blockIdx.x * 4 + wid;
    const float* row = doc + word * D;
    float acc = 0.f;
    for (int d = lane; d < D; d += 64) acc += row[d] * wh[d];
    #pragma unroll
    for (int o = 32; o; o >>= 1) acc += __shfl_down(acc, o);
    if (lane == 0) hs[word] = acc + bh[0];
}

// ---------- P4 = w_width_emb @ W1[1536:1556,:] ----------
__global__ __launch_bounds__(256) void k_p4(const float* __restrict__ wwe,
                                            const float* __restrict__ W1,
                                            float* __restrict__ P4) {
    int o = blockIdx.x * 256 + threadIdx.x;
    if (o >= 30 * FFNN) return;
    int wi = o / FFNN, j = o - wi * FFNN;
    float acc = 0.f;
    #pragma unroll
    for (int f = 0; f < FEAT; ++f) acc += wwe[wi * FEAT + f] * W1[(1536 + f) * FFNN + j];
    P4[o] = acc;
}

// ---------- split fp32 -> bf16 hi/lo ----------
__global__ __launch_bounds__(256) void k_split(const float* __restrict__ src,
                                               ushort* __restrict__ h,
                                               ushort* __restrict__ l, int n) {
    int i = blockIdx.x * 256 + threadIdx.x;
    if (i >= n) return;
    float v = src[i];
    ushort hi = f2b(v);
    float r = v - b2f(hi);
    h[i] = hi;
    l[i] = f2b(r);
}

// ---------- W1 slices: transpose + split -> W1T[z][1024 n][768 k] hi/lo ----------
__global__ void k_tw1(const float* __restrict__ W1,
                      ushort* __restrict__ TH, ushort* __restrict__ TL) {
    __shared__ float tile[32][33];
    int tx = threadIdx.x, ty = threadIdx.y;
    int k0 = blockIdx.x * 32, n0 = blockIdx.y * 32, z = blockIdx.z;
    int roff = (z == 0) ? 0 : (z == 1) ? 768 : 1556;
    #pragma unroll
    for (int i = 0; i < 4; ++i) {
        int kk = ty + i * 8;
        float v = (n0 + tx < FFNN) ? W1[(size_t)(roff + k0 + kk) * FFNN + n0 + tx] : 0.f;
        tile[kk][tx] = v;
    }
    __syncthreads();
    #pragma unroll
    for (int i = 0; i < 4; ++i) {
        int nn = ty + i * 8;
        float v = tile[tx][nn];
        ushort hi = f2b(v);
        float r = v - b2f(hi);
        size_t o = (size_t)z * 1024 * D + (size_t)(n0 + nn) * D + k0 + tx;
        TH[o] = hi;
        TL[o] = f2b(r);
    }
}

// ---------- W2: transpose + split -> W2T[1024 n][1000 k] hi/lo ----------
__global__ void k_tw2(const float* __restrict__ W2,
                      ushort* __restrict__ TH, ushort* __restrict__ TL) {
    __shared__ float tile[32][33];
    int tx = threadIdx.x, ty = threadIdx.y;
    int k0 = blockIdx.x * 32, n0 = blockIdx.y * 32;
    #pragma unroll
    for (int i = 0; i < 4; ++i) {
        int kk = ty + i * 8;
        float v = (k0 + kk < FFNN && n0 + tx < FFNN)
                    ? W2[(size_t)(k0 + kk) * FFNN + n0 + tx] : 0.f;
        tile[kk][tx] = v;
    }
    __syncthreads();
    #pragma unroll
    for (int i = 0; i < 4; ++i) {
        int nn = ty + i * 8;
        int k = k0 + tx;
        if (k < FFNN) {
            float v = tile[tx][nn];
            ushort hi = f2b(v);
            float r = v - b2f(hi);
            size_t o = (size_t)(n0 + nn) * FFNN + k;
            TH[o] = hi;
            TL[o] = f2b(r);
        }
    }
}

// ---------- MFMA GEMM: P[z] = doc @ W1slice  (XCD-swizzled, XOR-slot LDS) ----------
__global__ __launch_bounds__(256) void k_gemmPm(const ushort* __restrict__ Ah_g,
                                                const ushort* __restrict__ Al_g,
                                                const ushort* __restrict__ Bh_g,
                                                const ushort* __restrict__ Bl_g,
                                                float* __restrict__ Pout) {
    __shared__ ushort Ah[128 * 32], Al[128 * 32], Bh[128 * 32], Bl[128 * 32];
    int tid = threadIdx.x;
    // bijective XCD remap: 192 blocks = 8 XCD * 24
    int orig = blockIdx.x;
    int t = (orig & 7) * 24 + (orig >> 3);
    int z = t >> 6, rem = t & 63;
    int rowt = rem & 7, colt = rem >> 3;
    int row0 = rowt * 128, col0 = colt * 128;
    size_t zoff = (size_t)z * 1024 * D;
    const ushort* Bh_z = Bh_g + zoff;
    const ushort* Bl_z = Bl_g + zoff;
    float* C = Pout + (size_t)z * NW * FFNN;
    int w = tid >> 6, l = tid & 63;
    int wr = w >> 1, wc = w & 1;
    int fr = l & 15, kb = l >> 4;
    f32x4 acc[4][4] = {};
    for (int kt = 0; kt < D; kt += 32) {
        #pragma unroll
        for (int i = 0; i < 2; ++i) {
            int cid = tid + i * 256;
            int r = cid >> 2, p = cid & 3;
            int q = p ^ ((r >> 1) & 3);          // logical k-slot (global side)
            int kg = kt + q * 8;
            uint4 a0 = *(const uint4*)(Ah_g + (size_t)(row0 + r) * D + kg);
            uint4 a1 = *(const uint4*)(Al_g + (size_t)(row0 + r) * D + kg);
            uint4 b0 = *(const uint4*)(Bh_z + (size_t)(col0 + r) * D + kg);
            uint4 b1 = *(const uint4*)(Bl_z + (size_t)(col0 + r) * D + kg);
            int lo = r * 32 + p * 8;
            *(uint4*)&Ah[lo] = a0;
            *(uint4*)&Al[lo] = a1;
            *(uint4*)&Bh[lo] = b0;
            *(uint4*)&Bl[lo] = b1;
        }
        __syncthreads();
        bf16x8 af[4], alf[4], bfr[4], blf[4];
        #pragma unroll
        for (int mt = 0; mt < 4; ++mt) {
            int r = wr * 64 + mt * 16 + fr;
            int sl = (kb ^ ((r >> 1) & 3)) * 8;
            af[mt]  = *(const bf16x8*)&Ah[r * 32 + sl];
            alf[mt] = *(const bf16x8*)&Al[r * 32 + sl];
        }
        #pragma unroll
        for (int nt = 0; nt < 4; ++nt) {
            int c = wc * 64 + nt * 16 + fr;
            int sl = (kb ^ ((c >> 1) & 3)) * 8;
            bfr[nt] = *(const bf16x8*)&Bh[c * 32 + sl];
            blf[nt] = *(const bf16x8*)&Bl[c * 32 + sl];
        }
        #pragma unroll
        for (int mt = 0; mt < 4; ++mt)
            #pragma unroll
            for (int nt = 0; nt < 4; ++nt) {
                acc[mt][nt] = MFMA16(af[mt], bfr[nt], acc[mt][nt], 0, 0, 0);
                acc[mt][nt] = MFMA16(af[mt], blf[nt], acc[mt][nt], 0, 0, 0);
                acc[mt][nt] = MFMA16(alf[mt], bfr[nt], acc[mt][nt], 0, 0, 0);
            }
        __syncthreads();
    }
    #pragma unroll
    for (int mt = 0; mt < 4; ++mt)
        #pragma unroll
        for (int nt = 0; nt < 4; ++nt)
            #pragma unroll
            for (int r = 0; r < 4; ++r) {
                int row = row0 + wr * 64 + mt * 16 + kb * 4 + r;
                int col = col0 + wc * 64 + nt * 16 + fr;
                if (col < FFNN) C[(size_t)row * FFNN + col] = acc[mt][nt][r];
            }
}

// ---------- MFMA GEMM2 fused: relu(H1@W2+b2).W3 -> PS (XCD-swizzled, XOR LDS) ----------
__global__ __launch_bounds__(256) void k_gemm2m(const ushort* __restrict__ Ah_g,
                                                const ushort* __restrict__ Al_g,
                                                const ushort* __restrict__ Bh_g,
                                                const ushort* __restrict__ Bl_g,
                                                const float* __restrict__ b2,
                                                const float* __restrict__ W3,
                                                float* __restrict__ PS) {
    __shared__ ushort Ah[128 * 32], Al[128 * 32], Bh[128 * 32], Bl[128 * 32];
    int tid = threadIdx.x;
    // bijective XCD remap: 512 blocks = 8 XCD * 64; XCD owns 8-row band, rows fastest
    int orig = blockIdx.x;
    int xcd = orig & 7, idx = orig >> 3;
    int rowt = xcd * 8 + (idx & 7), colt = idx >> 3;
    int row0 = rowt * 128, col0 = colt * 128;
    int w = tid >> 6, l = tid & 63;
    int wr = w >> 1, wc = w & 1;
    int fr = l & 15, kb = l >> 4;
    f32x4 acc[4][4] = {};
    for (int kt = 0; kt < FFNN; kt += 32) {
        #pragma unroll
        for (int i = 0; i < 2; ++i) {
            int cid = tid + i * 256;
            int r = cid >> 2, p = cid & 3;
            int q = p ^ ((r >> 1) & 3);
            int kg = kt + q * 8;
            bool v = (kg + 7) < FFNN;
            uint4 zz = make_uint4(0, 0, 0, 0);
            uint4 a0 = v ? *(const uint4*)(Ah_g + (size_t)(row0 + r) * FFNN + kg) : zz;
            uint4 a1 = v ? *(const uint4*)(Al_g + (size_t)(row0 + r) * FFNN + kg) : zz;
            uint4 b0 = v ? *(const uint4*)(Bh_g + (size_t)(col0 + r) * FFNN + kg) : zz;
            uint4 b1 = v ? *(const uint4*)(Bl_g + (size_t)(col0 + r) * FFNN + kg) : zz;
            int lo = r * 32 + p * 8;
            *(uint4*)&Ah[lo] = a0;
            *(uint4*)&Al[lo] = a1;
            *(uint4*)&Bh[lo] = b0;
            *(uint4*)&Bl[lo] = b1;
        }
        __syncthreads();
        bf16x8 af[4], alf[4], bfr[4], blf[4];
        #pragma unroll
        for (int mt = 0; mt < 4; ++mt) {
            int r = wr * 64 + mt * 16 + fr;
            int sl = (kb ^ ((r >> 1) & 3)) * 8;
            af[mt]  = *(const bf16x8*)&Ah[r * 32 + sl];
            alf[mt] = *(const bf16x8*)&Al[r * 32 + sl];
        }
        #pragma unroll
        for (int nt = 0; nt < 4; ++nt) {
            int c = wc * 64 + nt * 16 + fr;
            int sl = (kb ^ ((c >> 1) & 3)) * 8;
            bfr[nt] = *(const bf16x8*)&Bh[c * 32 + sl];
            blf[nt] = *(const bf16x8*)&Bl[c * 32 + sl];
        }
        #pragma unroll
        for (int mt = 0; mt < 4; ++mt)
            #pragma unroll
            for (int nt = 0; nt < 4; ++nt) {
                acc[mt][nt] = MFMA16(af[mt], bfr[nt], acc[mt][nt], 0, 0, 0);
                acc[mt][nt] = MFMA16(af[mt], blf[nt], acc[mt][nt], 0, 0, 0);
                acc[mt][nt] = MFMA16(alf[mt], bfr[nt], acc[mt][nt], 0, 0, 0);
            }
        __syncthreads();
    }
    float w3v[4], b2v[4];
    #pragma unroll
    for (int nt = 0; nt < 4; ++nt) {
        int col = col0 + wc * 64 + nt * 16 + fr;
        bool cv = col < FFNN;
        w3v[nt] = cv ? W3[col] : 0.f;
        b2v[nt] = cv ? b2[col] : 0.f;
    }
    #pragma unroll
    for (int mt = 0; mt < 4; ++mt) {
        #pragma unroll
        for (int r = 0; r < 4; ++r) {
            float p = 0.f;
            #pragma unroll
            for (int nt = 0; nt < 4; ++nt) {
                float v = fmaxf(acc[mt][nt][r] + b2v[nt], 0.f);
                p = fmaf(v, w3v[nt], p);
            }
            p += __shfl_xor(p, 1);
            p += __shfl_xor(p, 2);
            p += __shfl_xor(p, 4);
            p += __shfl_xor(p, 8);
            if (fr == 0) {
                int row = row0 + wr * 64 + mt * 16 + kb * 4 + r;
                PS[row * 16 + colt * 2 + wc] = p;
            }
        }
    }
}

// ---------- attention weights per span ----------
__global__ __launch_bounds__(256) void k_attn(const float* __restrict__ hs,
                                              const int* __restrict__ starts,
                                              const int* __restrict__ ends,
                                              float* __restrict__ attn) {
    int s = blockIdx.x * 256 + threadIdx.x;
    if (s >= NS) return;
    int st = starts[s], en = ends[s];
    int width = en - st + 1;
    float v[MAXW];
    float mx = -3.0e38f;
    #pragma unroll
    for (int w = 0; w < MAXW; ++w) {
        int idx = st + w; if (idx > NW - 1) idx = NW - 1;
        float x = hs[idx];
        v[w] = (w < width) ? x : -3.0e38f;
        mx = fmaxf(mx, v[w]);
    }
    float sum = 0.f;
    #pragma unroll
    for (int w = 0; w < MAXW; ++w) { v[w] = expf(v[w] - mx); sum += v[w]; }
    float inv = 1.f / sum;
    #pragma unroll
    for (int w = 0; w < MAXW; ++w) attn[s * 32 + w] = v[w] * inv;
}

// ---------- h1 assembly: gather P rows + attended + bias + relu -> bf16 hi/lo ----------
__global__ __launch_bounds__(256) void k_h1(const float* __restrict__ P,
                                            const float* __restrict__ P4,
                                            const float* __restrict__ attn,
                                            const float* __restrict__ b1,
                                            const int* __restrict__ starts,
                                            const int* __restrict__ ends,
                                            ushort* __restrict__ H1h,
                                            ushort* __restrict__ H1l) {
    int s = blockIdx.x;
    int tid = threadIdx.x;
    if (tid >= 250) return;
    int st = starts[s], en = ends[s];
    int width = en - st + 1;
    const float4* P1r = (const float4*)(P + (size_t)st * FFNN);
    const float4* P2r = (const float4*)(P + (size_t)NW * FFNN + (size_t)en * FFNN);
    const float*  P3  = P + 2 * (size_t)NW * FFNN;
    const float4* P4r = (const float4*)(P4 + (size_t)(width - 1) * FFNN);
    const float4* b1v = (const float4*)b1;
    const float*  ar  = attn + s * 32;
    float4 a = P1r[tid], b = P2r[tid], c = P4r[tid], d = b1v[tid];
    float4 acc = {a.x + b.x + c.x + d.x,
                  a.y + b.y + c.y + d.y,
                  a.z + b.z + c.z + d.z,
                  a.w + b.w + c.w + d.w};
    for (int w = 0; w < width; ++w) {
        float aw = ar[w];
        float4 p3 = ((const float4*)(P3 + (size_t)(st + w) * FFNN))[tid];
        acc.x = fmaf(aw, p3.x, acc.x);
        acc.y = fmaf(aw, p3.y, acc.y);
        acc.z = fmaf(aw, p3.z, acc.z);
        acc.w = fmaf(aw, p3.w, acc.w);
    }
    float rv[4] = {fmaxf(acc.x, 0.f), fmaxf(acc.y, 0.f), fmaxf(acc.z, 0.f), fmaxf(acc.w, 0.f)};
    ushort4 hi, lo;
    ushort* hp = (ushort*)&hi;
    ushort* lp = (ushort*)&lo;
    #pragma unroll
    for (int j = 0; j < 4; ++j) {
        ushort h = f2b(rv[j]);
        float r = rv[j] - b2f(h);
        hp[j] = h;
        lp[j] = f2b(r);
    }
    *(ushort4*)(H1h + (size_t)s * FFNN + tid * 4) = hi;
    *(ushort4*)(H1l + (size_t)s * FFNN + tid * 4) = lo;
}

// ---------- final score: sum 16 partials + b3 ----------
__global__ __launch_bounds__(256) void k_score2(const float* __restrict__ PS,
                                                const float* __restrict__ b3,
                                                float* __restrict__ out) {
    int r = blockIdx.x * 256 + threadIdx.x;
    if (r >= NS) return;
    float s = 0.f;
    #pragma unroll
    for (int b = 0; b < 16; ++b) s += PS[r * 16 + b];
    out[r] = s + b3[0];
}

// ---------- tile-parallel rank: RANK[i] += #{j in tile bj : key[j] < key[i]} ----------
__global__ __launch_bounds__(256) void k_rankA(const float* __restrict__ scores,
                                               int* __restrict__ RANK) {
    __shared__ unsigned long long tile[256];
    int i = blockIdx.x * 256 + threadIdx.x;
    int j = blockIdx.y * 256 + threadIdx.x;
    unsigned uj = __float_as_uint(scores[j]);
    unsigned mj = (uj >> 31) ? ~uj : (uj | 0x80000000u);
    tile[threadIdx.x] = ((unsigned long long)(~mj) << 32) | (unsigned)j;
    __syncthreads();
    unsigned u = __float_as_uint(scores[i]);
    unsigned m = (u >> 31) ? ~u : (u | 0x80000000u);
    unsigned long long key = ((unsigned long long)(~m) << 32) | (unsigned)i;
    int r = 0;
    #pragma unroll 8
    for (int q = 0; q < 256; ++q) r += (tile[q] < key);
    if (r) atomicAdd(&RANK[i], r);
}

// ---------- scatter: pk[RANK[i]] = packed (span, start, end) ----------
__global__ __launch_bounds__(256) void k_rankB(const int* __restrict__ RANK,
                                               const int* __restrict__ starts,
                                               const int* __restrict__ ends,
                                               unsigned long long* __restrict__ pk) {
    int i = blockIdx.x * 256 + threadIdx.x;
    pk[RANK[i]] = ((unsigned long long)(unsigned)i << 32) |
                  ((unsigned)starts[i] << 16) | (unsigned)ends[i];
}

// ---------- parallel pairwise-mask precompute: one wave per 64-span chunk ----------
__global__ __launch_bounds__(64) void k_masks(const unsigned long long* __restrict__ pk,
                                              unsigned long long* __restrict__ MC,
                                              unsigned long long* __restrict__ ME,
                                              unsigned long long* __restrict__ MG) {
    int lane = threadIdx.x;
    int c = blockIdx.x;
    unsigned long long p = pk[c * 64 + lane];
    int s = (int)((p >> 16) & 0xFFFF);
    int e = (int)(p & 0xFFFF);
    unsigned long long conf = 0, eqm = 0, gtm = 0;
    for (int r = 1; r < 64; ++r) {
        int j = (lane + r) & 63;
        int sj = __shfl(s, j);
        int ej = __shfl(e, j);
        unsigned long long bit = 1ull << j;
        bool cross = ((sj > s) & (sj <= e) & (ej > e)) |
                     ((ej >= s) & (ej < e) & (sj < s));
        if (cross) conf |= bit;
        if (sj == s) { if (ej == e) eqm |= bit; else if (ej > e) gtm |= bit; }
    }
    MC[c * 64 + lane] = conf;
    ME[c * 64 + lane] = eqm;
    MG[c * 64 + lane] = gtm;
}

// ---------- greedy crossing-suppression scan (masks precomputed) ----------
__global__ __launch_bounds__(64) void k_scan(const unsigned long long* __restrict__ pk,
                                             const unsigned long long* __restrict__ MC,
                                             const unsigned long long* __restrict__ ME,
                                             const unsigned long long* __restrict__ MG,
                                             int top, int* __restrict__ SEL,
                                             int* __restrict__ SELKEY,
                                             int* __restrict__ CNT) {
    __shared__ int mxs[NW];
    __shared__ int mne[NW];
    __shared__ int mxe[NW];
    int lane = threadIdx.x;
    unsigned long long lower = (1ull << lane) - 1ull;
    for (int p = lane; p < NW; p += 64) { mxs[p] = -1; mne[p] = NW; mxe[p] = -1; }
    __syncthreads();
    int count = 0;
    unsigned long long pc = pk[lane];
    unsigned long long conf = MC[lane], eqm = ME[lane], gtm = MG[lane];
    for (int c = 0; c < NS / 64 && count < top; ++c) {
        unsigned long long pn = 0, cn = 0, en2 = 0, gn = 0;
        if (c + 1 < NS / 64) {
            int o = (c + 1) * 64 + lane;
            pn = pk[o]; cn = MC[o]; en2 = ME[o]; gn = MG[o];
        }
        int span = (int)(pc >> 32);
        int s = (int)((pc >> 16) & 0xFFFF);
        int e = (int)(pc & 0xFFFF);
        int bad = (mxs[e] > s) | (mne[s] < e);
        int g = mxe[s];
        bool gdup = (g == e), ggt = (g > e);
        unsigned long long pending = __ballot(!bad), committed = 0;
        unsigned long long relv = (conf | eqm | gtm) & lower;
        while (pending) {
            bool mine = (pending >> lane) & 1;
            bool ready = mine && ((pending & relv) == 0ull);
            unsigned long long cb = committed & lower;
            bool rej = (cb & conf) != 0ull;
            bool gt_any = ggt || ((cb & gtm) != 0ull);
            bool eq_any = gdup || ((cb & eqm) != 0ull);
            bool acc_now = ready && !rej && !(eq_any && !gt_any);
            committed |= __ballot(acc_now);
            pending &= ~__ballot(ready);
        }
        int allowed = top - count;
        while (__popcll(committed) > allowed)
            committed &= ~(1ull << (63 - __builtin_clzll(committed)));
        if ((committed >> lane) & 1) {
            int pos = count + __popcll(committed & lower);
            SEL[pos] = span;
            SELKEY[pos] = s * NW + e;
            atomicMax(&mxe[s], e);
            #pragma unroll
            for (int k = 0; k < MAXW - 1; ++k) {
                if (k < e - s) {
                    atomicMax(&mxs[s + k], s);
                    atomicMin(&mne[s + 1 + k], e);
                }
            }
        }
        count += __popcll(committed);
        __syncthreads();
        pc = pn; conf = cn; eqm = en2; gtm = gn;
    }
    if (lane == 0) *CNT = count;
}

// ---------- final sort: multi-wave rank sort of the selected spans ----------
__global__ __launch_bounds__(512) void k_sort(const int* __restrict__ SEL,
                                              const int* __restrict__ SELKEY,
                                              const int* __restrict__ CNT,
                                              int top, float* __restrict__ out_idx) {
    __shared__ int keys[512];
    __shared__ int vals[512];
    int cnt = *CNT;
    int r = threadIdx.x;
    if (r < top) {
        keys[r] = (r < cnt) ? SELKEY[r] : NW * NW;
        vals[r] = (r < cnt) ? SEL[r] : -1;
    }
    __syncthreads();
    if (r < top) {
        int kr = keys[r];
        int rank = 0;
        for (int q = 0; q < top; ++q) {
            int kq = keys[q];
            rank += (kq < kr) || (kq == kr && q < r);
        }
        out_idx[rank] = (float)vals[r];
    }
}

extern "C" void kernel_launch(void* const* d_in, const int* in_sizes, int n_in,
                              void* d_out, int out_size, void* d_ws, size_t ws_size,
                              hipStream_t stream) {
    const float* doc = (const float*)d_in[0];
    const float* wwe = (const float*)d_in[1];
    const float* wh  = (const float*)d_in[2];
    const float* bh  = (const float*)d_in[3];
    const float* W1  = (const float*)d_in[4];
    const float* b1  = (const float*)d_in[5];
    const float* W2  = (const float*)d_in[6];
    const float* b2  = (const float*)d_in[7];
    const float* W3  = (const float*)d_in[8];
    const float* b3  = (const float*)d_in[9];
    const int* starts = (const int*)d_in[10];
    const int* ends   = (const int*)d_in[11];
    int top = out_size - NS;                 // 409

    float* ws  = (float*)d_ws;
    float* P   = ws + O_P;
    float* P4  = ws + O_P4;
    float* HS  = ws + O_HS;
    float* ATT = ws + O_ATT;
    float* PS  = ws + O_PS;
    float* H1R = ws + O_H1R;
    ushort* H1H = (ushort*)H1R;
    ushort* H1L = (ushort*)(H1R + 4096000);
    ushort* W1TH = (ushort*)H1R;
    ushort* W1TL = (ushort*)(H1R + 1179648);
    ushort* DOCH = (ushort*)(H1R + 2359296);
    ushort* DOCL = (ushort*)(H1R + 2752512);
    ushort* W2TH = (ushort*)ws;
    ushort* W2TL = (ushort*)(ws + 512000);
    unsigned long long* PK = (unsigned long long*)H1R;   // dead after k_gemm2m
    int* SEL    = (int*)(ws + O_ATT);                    // ATT dead after k_h1
    int* SELKEY = SEL + 512;
    int* CNT    = SEL + 1024;
    int* RANK   = SEL + 2048;                            // 8192 ints
    unsigned long long* MC = (unsigned long long*)(ws + O_PS);   // PS dead after k_score2
    unsigned long long* ME = MC + NS;
    unsigned long long* MG = MC + 2 * NS;
    float* outs = (float*)d_out;

    k_head<<<NW / 4, 256, 0, stream>>>(doc, wh, bh, HS);
    k_p4<<<(30 * FFNN + 255) / 256, 256, 0, stream>>>(wwe, W1, P4);

    k_split<<<(NW * D + 255) / 256, 256, 0, stream>>>(doc, DOCH, DOCL, NW * D);
    {
        dim3 g(24, 32, 3), b(32, 8);
        k_tw1<<<g, b, 0, stream>>>(W1, W1TH, W1TL);
    }
    k_gemmPm<<<192, 256, 0, stream>>>(DOCH, DOCL, W1TH, W1TL, P);

    k_attn<<<NS / 256, 256, 0, stream>>>(HS, starts, ends, ATT);
    k_h1<<<NS, 256, 0, stream>>>(P, P4, ATT, b1, starts, ends, H1H, H1L);

    {
        dim3 g(32, 32), b(32, 8);
        k_tw2<<<g, b, 0, stream>>>(W2, W2TH, W2TL);
    }
    k_gemm2m<<<512, 256, 0, stream>>>(H1H, H1L, W2TH, W2TL, b2, W3, PS);

    k_score2<<<NS / 256, 256, 0, stream>>>(PS, b3, outs);

    hipMemsetAsync(RANK, 0, NS * sizeof(int), stream);
    {
        dim3 g(NS / 256, NS / 256);
        k_rankA<<<g, 256, 0, stream>>>(outs, RANK);
    }
    k_rankB<<<NS / 256, 256, 0, stream>>>(RANK, starts, ends, PK);
    k_masks<<<NS / 64, 64, 0, stream>>>(PK, MC, ME, MG);
    k_scan<<<1, 64, 0, stream>>>(PK, MC, ME, MG, top, SEL, SELKEY, CNT);
    k_sort<<<1, 512, 0, stream>>>(SEL, SELKEY, CNT, top, outs + NS);
}

// Round 12
// 232.552 us; speedup vs baseline: 2.4572x; 1.1508x over previous
//
#include <hip/hip_runtime.h>
#include <hip/hip_bf16.h>
#include <stdint.h>

#define NW   1024
#define D    768
#define NS   8192
#define MAXW 30
#define FFNN 1000
#define FEAT 20

typedef __attribute__((ext_vector_type(8))) short bf16x8;
typedef __attribute__((ext_vector_type(4))) float f32x4;
#define MFMA16 __builtin_amdgcn_mfma_f32_16x16x32_bf16

// ws layout (float-slot offsets)
#define O_P    0                          // 3*1024*1000 fp32 P1,P2,P3 (later W2T 1024-stride)
#define O_P4   3072000                    // 30*1000
#define O_HS   3102000                    // 1024
#define O_ATT  3103024                    // 8192*32 (ATT; later SEL/SELKEY/CNT/RANK)
#define O_PS   3365168                    // 8192*16 (PS; later MC/ME/MG masks)
#define O_H1R  3504432                    // H1 hi/lo bf16 (stride 1000); earlier W1T/DOC; later pk

__device__ inline ushort f2b(float v) {
    __hip_bfloat16 b = __float2bfloat16(v);
    return *(ushort*)&b;
}
__device__ inline float b2f(ushort u) {
    __hip_bfloat16 b = *(__hip_bfloat16*)&u;
    return __bfloat162float(b);
}

// ---------- head scores ----------
__global__ __launch_bounds__(256) void k_head(const float* __restrict__ doc,
                                              const float* __restrict__ wh,
                                              const float* __restrict__ bh,
                                              float* __restrict__ hs) {
    int wid = threadIdx.x >> 6, lane = threadIdx.x & 63;
    int word = blockIdx.x * 4 + wid;
    const float* row = doc + word * D;
    float acc = 0.f;
    for (int d = lane; d < D; d += 64) acc += row[d] * wh[d];
    #pragma unroll
    for (int o = 32; o; o >>= 1) acc += __shfl_down(acc, o);
    if (lane == 0) hs[word] = acc + bh[0];
}

// ---------- P4 = w_width_emb @ W1[1536:1556,:] ----------
__global__ __launch_bounds__(256) void k_p4(const float* __restrict__ wwe,
                                            const float* __restrict__ W1,
                                            float* __restrict__ P4) {
    int o = blockIdx.x * 256 + threadIdx.x;
    if (o >= 30 * FFNN) return;
    int wi = o / FFNN, j = o - wi * FFNN;
    float acc = 0.f;
    #pragma unroll
    for (int f = 0; f < FEAT; ++f) acc += wwe[wi * FEAT + f] * W1[(1536 + f) * FFNN + j];
    P4[o] = acc;
}

// ---------- split fp32 -> bf16 hi/lo ----------
__global__ __launch_bounds__(256) void k_split(const float* __restrict__ src,
                                               ushort* __restrict__ h,
                                               ushort* __restrict__ l, int n) {
    int i = blockIdx.x * 256 + threadIdx.x;
    if (i >= n) return;
    float v = src[i];
    ushort hi = f2b(v);
    float r = v - b2f(hi);
    h[i] = hi;
    l[i] = f2b(r);
}

// ---------- W1 slices: transpose + split -> W1T[z][1024 n][768 k] hi/lo ----------
__global__ void k_tw1(const float* __restrict__ W1,
                      ushort* __restrict__ TH, ushort* __restrict__ TL) {
    __shared__ float tile[32][33];
    int tx = threadIdx.x, ty = threadIdx.y;
    int k0 = blockIdx.x * 32, n0 = blockIdx.y * 32, z = blockIdx.z;
    int roff = (z == 0) ? 0 : (z == 1) ? 768 : 1556;
    #pragma unroll
    for (int i = 0; i < 4; ++i) {
        int kk = ty + i * 8;
        float v = (n0 + tx < FFNN) ? W1[(size_t)(roff + k0 + kk) * FFNN + n0 + tx] : 0.f;
        tile[kk][tx] = v;
    }
    __syncthreads();
    #pragma unroll
    for (int i = 0; i < 4; ++i) {
        int nn = ty + i * 8;
        float v = tile[tx][nn];
        ushort hi = f2b(v);
        float r = v - b2f(hi);
        size_t o = (size_t)z * 1024 * D + (size_t)(n0 + nn) * D + k0 + tx;
        TH[o] = hi;
        TL[o] = f2b(r);
    }
}

// ---------- W2: transpose + split -> W2T[1024 n][1024 k] hi/lo, zero-padded k ----------
__global__ void k_tw2(const float* __restrict__ W2,
                      ushort* __restrict__ TH, ushort* __restrict__ TL) {
    __shared__ float tile[32][33];
    int tx = threadIdx.x, ty = threadIdx.y;
    int k0 = blockIdx.x * 32, n0 = blockIdx.y * 32;
    #pragma unroll
    for (int i = 0; i < 4; ++i) {
        int kk = ty + i * 8;
        float v = (k0 + kk < FFNN && n0 + tx < FFNN)
                    ? W2[(size_t)(k0 + kk) * FFNN + n0 + tx] : 0.f;
        tile[kk][tx] = v;
    }
    __syncthreads();
    #pragma unroll
    for (int i = 0; i < 4; ++i) {
        int nn = ty + i * 8;
        int k = k0 + tx;
        float v = tile[tx][nn];               // 0 for k>=FFNN or n>=FFNN
        ushort hi = f2b(v);
        float r = v - b2f(hi);
        size_t o = (size_t)(n0 + nn) * 1024 + k;
        TH[o] = hi;
        TL[o] = f2b(r);
    }
}

// ---------- MFMA GEMM: P[z] = doc @ W1slice  (dbuf + global_load_lds) ----------
__global__ __launch_bounds__(256) void k_gemmPm(const ushort* __restrict__ Ah_g,
                                                const ushort* __restrict__ Al_g,
                                                const ushort* __restrict__ Bh_g,
                                                const ushort* __restrict__ Bl_g,
                                                float* __restrict__ Pout) {
    __shared__ ushort LDS[2][4][128 * 32];
    int tid = threadIdx.x;
    int orig = blockIdx.x;                    // 192 = 8 XCD * 24
    int t = (orig & 7) * 24 + (orig >> 3);
    int z = t >> 6, rem = t & 63;
    int rowt = rem & 7, colt = rem >> 3;
    int row0 = rowt * 128, col0 = colt * 128;
    size_t zoff = (size_t)z * 1024 * D;
    const ushort* Bh_z = Bh_g + zoff;
    const ushort* Bl_z = Bl_g + zoff;
    float* C = Pout + (size_t)z * NW * FFNN;
    int w = tid >> 6, l = tid & 63;
    int wr = w >> 1, wc = w & 1;
    int fr = l & 15, kb = l >> 4;
    // staging geometry: cid in [0,512), r=cid>>2, p=cid&3, lds byte off = cid*16 (linear)
    int r0 = tid >> 2, p = tid & 3;
    int r1 = r0 + 64;
    int q0 = p ^ ((r0 >> 1) & 3);
    int q1 = p ^ ((r1 >> 1) & 3);
    int base0 = (w * 64) * 8;                 // ushort units, wave-uniform
    int base1 = (256 + w * 64) * 8;
    f32x4 acc[4][4] = {};
    int cur = 0;
    #define STAGE_P(d, kt)                                                                  \
        do {                                                                                \
            int kg0 = (kt) + q0 * 8, kg1 = (kt) + q1 * 8;                                   \
            __builtin_amdgcn_global_load_lds((const uint*)(Ah_g + (size_t)(row0 + r0) * D + kg0), (uint*)&LDS[d][0][base0], 16, 0, 0); \
            __builtin_amdgcn_global_load_lds((const uint*)(Al_g + (size_t)(row0 + r0) * D + kg0), (uint*)&LDS[d][1][base0], 16, 0, 0); \
            __builtin_amdgcn_global_load_lds((const uint*)(Bh_z + (size_t)(col0 + r0) * D + kg0), (uint*)&LDS[d][2][base0], 16, 0, 0); \
            __builtin_amdgcn_global_load_lds((const uint*)(Bl_z + (size_t)(col0 + r0) * D + kg0), (uint*)&LDS[d][3][base0], 16, 0, 0); \
            __builtin_amdgcn_global_load_lds((const uint*)(Ah_g + (size_t)(row0 + r1) * D + kg1), (uint*)&LDS[d][0][base1], 16, 0, 0); \
            __builtin_amdgcn_global_load_lds((const uint*)(Al_g + (size_t)(row0 + r1) * D + kg1), (uint*)&LDS[d][1][base1], 16, 0, 0); \
            __builtin_amdgcn_global_load_lds((const uint*)(Bh_z + (size_t)(col0 + r1) * D + kg1), (uint*)&LDS[d][2][base1], 16, 0, 0); \
            __builtin_amdgcn_global_load_lds((const uint*)(Bl_z + (size_t)(col0 + r1) * D + kg1), (uint*)&LDS[d][3][base1], 16, 0, 0); \
        } while (0)
    STAGE_P(0, 0);
    __syncthreads();
    for (int kt = 0; kt < D; kt += 32) {
        if (kt + 32 < D) STAGE_P(cur ^ 1, kt + 32);
        bf16x8 af[4], alf[4], bfr[4], blf[4];
        #pragma unroll
        for (int mt = 0; mt < 4; ++mt) {
            int r = wr * 64 + mt * 16 + fr;
            int sl = (kb ^ ((r >> 1) & 3)) * 8;
            af[mt]  = *(const bf16x8*)&LDS[cur][0][r * 32 + sl];
            alf[mt] = *(const bf16x8*)&LDS[cur][1][r * 32 + sl];
        }
        #pragma unroll
        for (int nt = 0; nt < 4; ++nt) {
            int c = wc * 64 + nt * 16 + fr;
            int sl = (kb ^ ((c >> 1) & 3)) * 8;
            bfr[nt] = *(const bf16x8*)&LDS[cur][2][c * 32 + sl];
            blf[nt] = *(const bf16x8*)&LDS[cur][3][c * 32 + sl];
        }
        #pragma unroll
        for (int mt = 0; mt < 4; ++mt)
            #pragma unroll
            for (int nt = 0; nt < 4; ++nt) {
                acc[mt][nt] = MFMA16(af[mt], bfr[nt], acc[mt][nt], 0, 0, 0);
                acc[mt][nt] = MFMA16(af[mt], blf[nt], acc[mt][nt], 0, 0, 0);
                acc[mt][nt] = MFMA16(alf[mt], bfr[nt], acc[mt][nt], 0, 0, 0);
            }
        __syncthreads();
        cur ^= 1;
    }
    #pragma unroll
    for (int mt = 0; mt < 4; ++mt)
        #pragma unroll
        for (int nt = 0; nt < 4; ++nt)
            #pragma unroll
            for (int r = 0; r < 4; ++r) {
                int row = row0 + wr * 64 + mt * 16 + kb * 4 + r;
                int col = col0 + wc * 64 + nt * 16 + fr;
                if (col < FFNN) C[(size_t)row * FFNN + col] = acc[mt][nt][r];
            }
}

// ---------- MFMA GEMM2 fused: relu(H1@W2+b2).W3 -> PS (dbuf + global_load_lds) ----------
// A stride 1000 (tail reads garbage, zeroed by B pad); B stride 1024 zero-padded.
__global__ __launch_bounds__(256) void k_gemm2m(const ushort* __restrict__ Ah_g,
                                                const ushort* __restrict__ Al_g,
                                                const ushort* __restrict__ Bh_g,
                                                const ushort* __restrict__ Bl_g,
                                                const float* __restrict__ b2,
                                                const float* __restrict__ W3,
                                                float* __restrict__ PS) {
    __shared__ ushort LDS[2][4][128 * 32];
    int tid = threadIdx.x;
    int orig = blockIdx.x;                    // 512 = 8 XCD * 64; XCD owns 8-row band
    int xcd = orig & 7, idx = orig >> 3;
    int rowt = xcd * 8 + (idx & 7), colt = idx >> 3;
    int row0 = rowt * 128, col0 = colt * 128;
    int w = tid >> 6, l = tid & 63;
    int wr = w >> 1, wc = w & 1;
    int fr = l & 15, kb = l >> 4;
    int r0 = tid >> 2, p = tid & 3;
    int r1 = r0 + 64;
    int q0 = p ^ ((r0 >> 1) & 3);
    int q1 = p ^ ((r1 >> 1) & 3);
    int base0 = (w * 64) * 8;
    int base1 = (256 + w * 64) * 8;
    f32x4 acc[4][4] = {};
    int cur = 0;
    #define STAGE_2(d, kt)                                                                  \
        do {                                                                                \
            int kg0 = (kt) + q0 * 8, kg1 = (kt) + q1 * 8;                                   \
            __builtin_amdgcn_global_load_lds((const uint*)(Ah_g + (size_t)(row0 + r0) * 1000 + kg0), (uint*)&LDS[d][0][base0], 16, 0, 0); \
            __builtin_amdgcn_global_load_lds((const uint*)(Al_g + (size_t)(row0 + r0) * 1000 + kg0), (uint*)&LDS[d][1][base0], 16, 0, 0); \
            __builtin_amdgcn_global_load_lds((const uint*)(Bh_g + (size_t)(col0 + r0) * 1024 + kg0), (uint*)&LDS[d][2][base0], 16, 0, 0); \
            __builtin_amdgcn_global_load_lds((const uint*)(Bl_g + (size_t)(col0 + r0) * 1024 + kg0), (uint*)&LDS[d][3][base0], 16, 0, 0); \
            __builtin_amdgcn_global_load_lds((const uint*)(Ah_g + (size_t)(row0 + r1) * 1000 + kg1), (uint*)&LDS[d][0][base1], 16, 0, 0); \
            __builtin_amdgcn_global_load_lds((const uint*)(Al_g + (size_t)(row0 + r1) * 1000 + kg1), (uint*)&LDS[d][1][base1], 16, 0, 0); \
            __builtin_amdgcn_global_load_lds((const uint*)(Bh_g + (size_t)(col0 + r1) * 1024 + kg1), (uint*)&LDS[d][2][base1], 16, 0, 0); \
            __builtin_amdgcn_global_load_lds((const uint*)(Bl_g + (size_t)(col0 + r1) * 1024 + kg1), (uint*)&LDS[d][3][base1], 16, 0, 0); \
        } while (0)
    STAGE_2(0, 0);
    __syncthreads();
    for (int kt = 0; kt < 1024; kt += 32) {
        if (kt + 32 < 1024) STAGE_2(cur ^ 1, kt + 32);
        bf16x8 af[4], alf[4], bfr[4], blf[4];
        #pragma unroll
        for (int mt = 0; mt < 4; ++mt) {
            int r = wr * 64 + mt * 16 + fr;
            int sl = (kb ^ ((r >> 1) & 3)) * 8;
            af[mt]  = *(const bf16x8*)&LDS[cur][0][r * 32 + sl];
            alf[mt] = *(const bf16x8*)&LDS[cur][1][r * 32 + sl];
        }
        #pragma unroll
        for (int nt = 0; nt < 4; ++nt) {
            int c = wc * 64 + nt * 16 + fr;
            int sl = (kb ^ ((c >> 1) & 3)) * 8;
            bfr[nt] = *(const bf16x8*)&LDS[cur][2][c * 32 + sl];
            blf[nt] = *(const bf16x8*)&LDS[cur][3][c * 32 + sl];
        }
        #pragma unroll
        for (int mt = 0; mt < 4; ++mt)
            #pragma unroll
            for (int nt = 0; nt < 4; ++nt) {
                acc[mt][nt] = MFMA16(af[mt], bfr[nt], acc[mt][nt], 0, 0, 0);
                acc[mt][nt] = MFMA16(af[mt], blf[nt], acc[mt][nt], 0, 0, 0);
                acc[mt][nt] = MFMA16(alf[mt], bfr[nt], acc[mt][nt], 0, 0, 0);
            }
        __syncthreads();
        cur ^= 1;
    }
    float w3v[4], b2v[4];
    #pragma unroll
    for (int nt = 0; nt < 4; ++nt) {
        int col = col0 + wc * 64 + nt * 16 + fr;
        bool cv = col < FFNN;
        w3v[nt] = cv ? W3[col] : 0.f;
        b2v[nt] = cv ? b2[col] : 0.f;
    }
    #pragma unroll
    for (int mt = 0; mt < 4; ++mt) {
        #pragma unroll
        for (int r = 0; r < 4; ++r) {
            float pp = 0.f;
            #pragma unroll
            for (int nt = 0; nt < 4; ++nt) {
                float v = fmaxf(acc[mt][nt][r] + b2v[nt], 0.f);
                pp = fmaf(v, w3v[nt], pp);
            }
            pp += __shfl_xor(pp, 1);
            pp += __shfl_xor(pp, 2);
            pp += __shfl_xor(pp, 4);
            pp += __shfl_xor(pp, 8);
            if (fr == 0) {
                int row = row0 + wr * 64 + mt * 16 + kb * 4 + r;
                PS[row * 16 + colt * 2 + wc] = pp;
            }
        }
    }
}

// ---------- attention weights per span ----------
__global__ __launch_bounds__(256) void k_attn(const float* __restrict__ hs,
                                              const int* __restrict__ starts,
                                              const int* __restrict__ ends,
                                              float* __restrict__ attn) {
    int s = blockIdx.x * 256 + threadIdx.x;
    if (s >= NS) return;
    int st = starts[s], en = ends[s];
    int width = en - st + 1;
    float v[MAXW];
    float mx = -3.0e38f;
    #pragma unroll
    for (int w = 0; w < MAXW; ++w) {
        int idx = st + w; if (idx > NW - 1) idx = NW - 1;
        float x = hs[idx];
        v[w] = (w < width) ? x : -3.0e38f;
        mx = fmaxf(mx, v[w]);
    }
    float sum = 0.f;
    #pragma unroll
    for (int w = 0; w < MAXW; ++w) { v[w] = expf(v[w] - mx); sum += v[w]; }
    float inv = 1.f / sum;
    #pragma unroll
    for (int w = 0; w < MAXW; ++w) attn[s * 32 + w] = v[w] * inv;
}

// ---------- h1 assembly: gather P rows + attended + bias + relu -> bf16 hi/lo ----------
__global__ __launch_bounds__(256) void k_h1(const float* __restrict__ P,
                                            const float* __restrict__ P4,
                                            const float* __restrict__ attn,
                                            const float* __restrict__ b1,
                                            const int* __restrict__ starts,
                                            const int* __restrict__ ends,
                                            ushort* __restrict__ H1h,
                                            ushort* __restrict__ H1l) {
    int s = blockIdx.x;
    int tid = threadIdx.x;
    if (tid >= 250) return;
    int st = starts[s], en = ends[s];
    int width = en - st + 1;
    const float4* P1r = (const float4*)(P + (size_t)st * FFNN);
    const float4* P2r = (const float4*)(P + (size_t)NW * FFNN + (size_t)en * FFNN);
    const float*  P3  = P + 2 * (size_t)NW * FFNN;
    const float4* P4r = (const float4*)(P4 + (size_t)(width - 1) * FFNN);
    const float4* b1v = (const float4*)b1;
    const float*  ar  = attn + s * 32;
    float4 a = P1r[tid], b = P2r[tid], c = P4r[tid], d = b1v[tid];
    float4 acc = {a.x + b.x + c.x + d.x,
                  a.y + b.y + c.y + d.y,
                  a.z + b.z + c.z + d.z,
                  a.w + b.w + c.w + d.w};
    for (int w = 0; w < width; ++w) {
        float aw = ar[w];
        float4 p3 = ((const float4*)(P3 + (size_t)(st + w) * FFNN))[tid];
        acc.x = fmaf(aw, p3.x, acc.x);
        acc.y = fmaf(aw, p3.y, acc.y);
        acc.z = fmaf(aw, p3.z, acc.z);
        acc.w = fmaf(aw, p3.w, acc.w);
    }
    float rv[4] = {fmaxf(acc.x, 0.f), fmaxf(acc.y, 0.f), fmaxf(acc.z, 0.f), fmaxf(acc.w, 0.f)};
    ushort4 hi, lo;
    ushort* hp = (ushort*)&hi;
    ushort* lp = (ushort*)&lo;
    #pragma unroll
    for (int j = 0; j < 4; ++j) {
        ushort h = f2b(rv[j]);
        float r = rv[j] - b2f(h);
        hp[j] = h;
        lp[j] = f2b(r);
    }
    *(ushort4*)(H1h + (size_t)s * FFNN + tid * 4) = hi;
    *(ushort4*)(H1l + (size_t)s * FFNN + tid * 4) = lo;
}

// ---------- final score: sum 16 partials + b3 ----------
__global__ __launch_bounds__(256) void k_score2(const float* __restrict__ PS,
                                                const float* __restrict__ b3,
                                                float* __restrict__ out) {
    int r = blockIdx.x * 256 + threadIdx.x;
    if (r >= NS) return;
    float s = 0.f;
    #pragma unroll
    for (int b = 0; b < 16; ++b) s += PS[r * 16 + b];
    out[r] = s + b3[0];
}

// ---------- tile-parallel rank ----------
__global__ __launch_bounds__(256) void k_rankA(const float* __restrict__ scores,
                                               int* __restrict__ RANK) {
    __shared__ unsigned long long tile[256];
    int i = blockIdx.x * 256 + threadIdx.x;
    int j = blockIdx.y * 256 + threadIdx.x;
    unsigned uj = __float_as_uint(scores[j]);
    unsigned mj = (uj >> 31) ? ~uj : (uj | 0x80000000u);
    tile[threadIdx.x] = ((unsigned long long)(~mj) << 32) | (unsigned)j;
    __syncthreads();
    unsigned u = __float_as_uint(scores[i]);
    unsigned m = (u >> 31) ? ~u : (u | 0x80000000u);
    unsigned long long key = ((unsigned long long)(~m) << 32) | (unsigned)i;
    int r = 0;
    #pragma unroll 8
    for (int q = 0; q < 256; ++q) r += (tile[q] < key);
    if (r) atomicAdd(&RANK[i], r);
}

// ---------- scatter: pk[RANK[i]] = packed (span, start, end) ----------
__global__ __launch_bounds__(256) void k_rankB(const int* __restrict__ RANK,
                                               const int* __restrict__ starts,
                                               const int* __restrict__ ends,
                                               unsigned long long* __restrict__ pk) {
    int i = blockIdx.x * 256 + threadIdx.x;
    pk[RANK[i]] = ((unsigned long long)(unsigned)i << 32) |
                  ((unsigned)starts[i] << 16) | (unsigned)ends[i];
}

// ---------- parallel pairwise-mask precompute ----------
__global__ __launch_bounds__(64) void k_masks(const unsigned long long* __restrict__ pk,
                                              unsigned long long* __restrict__ MC,
                                              unsigned long long* __restrict__ ME,
                                              unsigned long long* __restrict__ MG) {
    int lane = threadIdx.x;
    int c = blockIdx.x;
    unsigned long long p = pk[c * 64 + lane];
    int s = (int)((p >> 16) & 0xFFFF);
    int e = (int)(p & 0xFFFF);
    unsigned long long conf = 0, eqm = 0, gtm = 0;
    for (int r = 1; r < 64; ++r) {
        int j = (lane + r) & 63;
        int sj = __shfl(s, j);
        int ej = __shfl(e, j);
        unsigned long long bit = 1ull << j;
        bool cross = ((sj > s) & (sj <= e) & (ej > e)) |
                     ((ej >= s) & (ej < e) & (sj < s));
        if (cross) conf |= bit;
        if (sj == s) { if (ej == e) eqm |= bit; else if (ej > e) gtm |= bit; }
    }
    MC[c * 64 + lane] = conf;
    ME[c * 64 + lane] = eqm;
    MG[c * 64 + lane] = gtm;
}

// ---------- greedy crossing-suppression scan (masks precomputed) ----------
__global__ __launch_bounds__(64) void k_scan(const unsigned long long* __restrict__ pk,
                                             const unsigned long long* __restrict__ MC,
                                             const unsigned long long* __restrict__ ME,
                                             const unsigned long long* __restrict__ MG,
                                             int top, int* __restrict__ SEL,
                                             int* __restrict__ SELKEY,
                                             int* __restrict__ CNT) {
    __shared__ int mxs[NW];
    __shared__ int mne[NW];
    __shared__ int mxe[NW];
    int lane = threadIdx.x;
    unsigned long long lower = (1ull << lane) - 1ull;
    for (int p = lane; p < NW; p += 64) { mxs[p] = -1; mne[p] = NW; mxe[p] = -1; }
    __syncthreads();
    int count = 0;
    unsigned long long pc = pk[lane];
    unsigned long long conf = MC[lane], eqm = ME[lane], gtm = MG[lane];
    for (int c = 0; c < NS / 64 && count < top; ++c) {
        unsigned long long pn = 0, cn = 0, en2 = 0, gn = 0;
        if (c + 1 < NS / 64) {
            int o = (c + 1) * 64 + lane;
            pn = pk[o]; cn = MC[o]; en2 = ME[o]; gn = MG[o];
        }
        int span = (int)(pc >> 32);
        int s = (int)((pc >> 16) & 0xFFFF);
        int e = (int)(pc & 0xFFFF);
        int bad = (mxs[e] > s) | (mne[s] < e);
        int g = mxe[s];
        bool gdup = (g == e), ggt = (g > e);
        unsigned long long pending = __ballot(!bad), committed = 0;
        unsigned long long relv = (conf | eqm | gtm) & lower;
        while (pending) {
            bool mine = (pending >> lane) & 1;
            bool ready = mine && ((pending & relv) == 0ull);
            unsigned long long cb = committed & lower;
            bool rej = (cb & conf) != 0ull;
            bool gt_any = ggt || ((cb & gtm) != 0ull);
            bool eq_any = gdup || ((cb & eqm) != 0ull);
            bool acc_now = ready && !rej && !(eq_any && !gt_any);
            committed |= __ballot(acc_now);
            pending &= ~__ballot(ready);
        }
        int allowed = top - count;
        while (__popcll(committed) > allowed)
            committed &= ~(1ull << (63 - __builtin_clzll(committed)));
        if ((committed >> lane) & 1) {
            int pos = count + __popcll(committed & lower);
            SEL[pos] = span;
            SELKEY[pos] = s * NW + e;
            atomicMax(&mxe[s], e);
            #pragma unroll
            for (int k = 0; k < MAXW - 1; ++k) {
                if (k < e - s) {
                    atomicMax(&mxs[s + k], s);
                    atomicMin(&mne[s + 1 + k], e);
                }
            }
        }
        count += __popcll(committed);
        __syncthreads();
        pc = pn; conf = cn; eqm = en2; gtm = gn;
    }
    if (lane == 0) *CNT = count;
}

// ---------- final sort: multi-wave rank sort of the selected spans ----------
__global__ __launch_bounds__(512) void k_sort(const int* __restrict__ SEL,
                                              const int* __restrict__ SELKEY,
                                              const int* __restrict__ CNT,
                                              int top, float* __restrict__ out_idx) {
    __shared__ int keys[512];
    __shared__ int vals[512];
    int cnt = *CNT;
    int r = threadIdx.x;
    if (r < top) {
        keys[r] = (r < cnt) ? SELKEY[r] : NW * NW;
        vals[r] = (r < cnt) ? SEL[r] : -1;
    }
    __syncthreads();
    if (r < top) {
        int kr = keys[r];
        int rank = 0;
        for (int q = 0; q < top; ++q) {
            int kq = keys[q];
            rank += (kq < kr) || (kq == kr && q < r);
        }
        out_idx[rank] = (float)vals[r];
    }
}

extern "C" void kernel_launch(void* const* d_in, const int* in_sizes, int n_in,
                              void* d_out, int out_size, void* d_ws, size_t ws_size,
                              hipStream_t stream) {
    const float* doc = (const float*)d_in[0];
    const float* wwe = (const float*)d_in[1];
    const float* wh  = (const float*)d_in[2];
    const float* bh  = (const float*)d_in[3];
    const float* W1  = (const float*)d_in[4];
    const float* b1  = (const float*)d_in[5];
    const float* W2  = (const float*)d_in[6];
    const float* b2  = (const float*)d_in[7];
    const float* W3  = (const float*)d_in[8];
    const float* b3  = (const float*)d_in[9];
    const int* starts = (const int*)d_in[10];
    const int* ends   = (const int*)d_in[11];
    int top = out_size - NS;                 // 409

    float* ws  = (float*)d_ws;
    float* P   = ws + O_P;
    float* P4  = ws + O_P4;
    float* HS  = ws + O_HS;
    float* ATT = ws + O_ATT;
    float* PS  = ws + O_PS;
    float* H1R = ws + O_H1R;
    ushort* H1H = (ushort*)H1R;
    ushort* H1L = (ushort*)(H1R + 4096000);
    ushort* W1TH = (ushort*)H1R;
    ushort* W1TL = (ushort*)(H1R + 1179648);
    ushort* DOCH = (ushort*)(H1R + 2359296);
    ushort* DOCL = (ushort*)(H1R + 2752512);
    ushort* W2TH = (ushort*)ws;                          // 1024*1024 ushorts
    ushort* W2TL = (ushort*)(ws + 524288);
    unsigned long long* PK = (unsigned long long*)H1R;   // dead after k_gemm2m
    int* SEL    = (int*)(ws + O_ATT);                    // ATT dead after k_h1
    int* SELKEY = SEL + 512;
    int* CNT    = SEL + 1024;
    int* RANK   = SEL + 2048;                            // 8192 ints
    unsigned long long* MC = (unsigned long long*)(ws + O_PS);   // PS dead after k_score2
    unsigned long long* ME = MC + NS;
    unsigned long long* MG = MC + 2 * NS;
    float* outs = (float*)d_out;

    k_head<<<NW / 4, 256, 0, stream>>>(doc, wh, bh, HS);
    k_p4<<<(30 * FFNN + 255) / 256, 256, 0, stream>>>(wwe, W1, P4);

    k_split<<<(NW * D + 255) / 256, 256, 0, stream>>>(doc, DOCH, DOCL, NW * D);
    {
        dim3 g(24, 32, 3), b(32, 8);
        k_tw1<<<g, b, 0, stream>>>(W1, W1TH, W1TL);
    }
    k_gemmPm<<<192, 256, 0, stream>>>(DOCH, DOCL, W1TH, W1TL, P);

    k_attn<<<NS / 256, 256, 0, stream>>>(HS, starts, ends, ATT);
    k_h1<<<NS, 256, 0, stream>>>(P, P4, ATT, b1, starts, ends, H1H, H1L);

    {
        dim3 g(32, 32), b(32, 8);
        k_tw2<<<g, b, 0, stream>>>(W2, W2TH, W2TL);
    }
    k_gemm2m<<<512, 256, 0, stream>>>(H1H, H1L, W2TH, W2TL, b2, W3, PS);

    k_score2<<<NS / 256, 256, 0, stream>>>(PS, b3, outs);

    hipMemsetAsync(RANK, 0, NS * sizeof(int), stream);
    {
        dim3 g(NS / 256, NS / 256);
        k_rankA<<<g, 256, 0, stream>>>(outs, RANK);
    }
    k_rankB<<<NS / 256, 256, 0, stream>>>(RANK, starts, ends, PK);
    k_masks<<<NS / 64, 64, 0, stream>>>(PK, MC, ME, MG);
    k_scan<<<1, 64, 0, stream>>>(PK, MC, ME, MG, top, SEL, SELKEY, CNT);
    k_sort<<<1, 512, 0, stream>>>(SEL, SELKEY, CNT, top, outs + NS);
}

// Round 13
// 231.294 us; speedup vs baseline: 2.4705x; 1.0054x over previous
//
#include <hip/hip_runtime.h>
#include <hip/hip_bf16.h>
#include <stdint.h>

#define NW   1024
#define D    768
#define NS   8192
#define MAXW 30
#define FFNN 1000
#define FEAT 20

typedef __attribute__((ext_vector_type(8))) short bf16x8;
typedef __attribute__((ext_vector_type(4))) float f32x4;
#define MFMA16 __builtin_amdgcn_mfma_f32_16x16x32_bf16

// ws layout (float-slot offsets)
#define O_P    0                          // 3*1024*1000 fp32 P1,P2,P3 (later W2T 1024-stride)
#define O_P4   3072000                    // 30*1000
#define O_HS   3102000                    // 1024
#define O_ATT  3103024                    // (SEL/SELKEY/CNT/RANK region)
#define O_PS   3365168                    // 8192*16 (PS; later MC/ME/MG masks)
#define O_H1R  3504432                    // H1 hi/lo bf16 (stride 1000); earlier W1T/DOC; later pk

__device__ inline ushort f2b(float v) {
    __hip_bfloat16 b = __float2bfloat16(v);
    return *(ushort*)&b;
}
__device__ inline float b2f(ushort u) {
    __hip_bfloat16 b = *(__hip_bfloat16*)&u;
    return __bfloat162float(b);
}

// ---------- head scores ----------
__global__ __launch_bounds__(256) void k_head(const float* __restrict__ doc,
                                              const float* __restrict__ wh,
                                              const float* __restrict__ bh,
                                              float* __restrict__ hs) {
    int wid = threadIdx.x >> 6, lane = threadIdx.x & 63;
    int word = blockIdx.x * 4 + wid;
    const float* row = doc + word * D;
    float acc = 0.f;
    for (int d = lane; d < D; d += 64) acc += row[d] * wh[d];
    #pragma unroll
    for (int o = 32; o; o >>= 1) acc += __shfl_down(acc, o);
    if (lane == 0) hs[word] = acc + bh[0];
}

// ---------- P4 = w_width_emb @ W1[1536:1556,:] ----------
__global__ __launch_bounds__(256) void k_p4(const float* __restrict__ wwe,
                                            const float* __restrict__ W1,
                                            float* __restrict__ P4) {
    int o = blockIdx.x * 256 + threadIdx.x;
    if (o >= 30 * FFNN) return;
    int wi = o / FFNN, j = o - wi * FFNN;
    float acc = 0.f;
    #pragma unroll
    for (int f = 0; f < FEAT; ++f) acc += wwe[wi * FEAT + f] * W1[(1536 + f) * FFNN + j];
    P4[o] = acc;
}

// ---------- split fp32 -> bf16 hi/lo ----------
__global__ __launch_bounds__(256) void k_split(const float* __restrict__ src,
                                               ushort* __restrict__ h,
                                               ushort* __restrict__ l, int n) {
    int i = blockIdx.x * 256 + threadIdx.x;
    if (i >= n) return;
    float v = src[i];
    ushort hi = f2b(v);
    float r = v - b2f(hi);
    h[i] = hi;
    l[i] = f2b(r);
}

// ---------- W1 slices: transpose + split -> W1T[z][1024 n][768 k] hi/lo ----------
__global__ void k_tw1(const float* __restrict__ W1,
                      ushort* __restrict__ TH, ushort* __restrict__ TL) {
    __shared__ float tile[32][33];
    int tx = threadIdx.x, ty = threadIdx.y;
    int k0 = blockIdx.x * 32, n0 = blockIdx.y * 32, z = blockIdx.z;
    int roff = (z == 0) ? 0 : (z == 1) ? 768 : 1556;
    #pragma unroll
    for (int i = 0; i < 4; ++i) {
        int kk = ty + i * 8;
        float v = (n0 + tx < FFNN) ? W1[(size_t)(roff + k0 + kk) * FFNN + n0 + tx] : 0.f;
        tile[kk][tx] = v;
    }
    __syncthreads();
    #pragma unroll
    for (int i = 0; i < 4; ++i) {
        int nn = ty + i * 8;
        float v = tile[tx][nn];
        ushort hi = f2b(v);
        float r = v - b2f(hi);
        size_t o = (size_t)z * 1024 * D + (size_t)(n0 + nn) * D + k0 + tx;
        TH[o] = hi;
        TL[o] = f2b(r);
    }
}

// ---------- W2: transpose + split -> W2T[1024 n][1024 k] hi/lo, zero-padded k ----------
__global__ void k_tw2(const float* __restrict__ W2,
                      ushort* __restrict__ TH, ushort* __restrict__ TL) {
    __shared__ float tile[32][33];
    int tx = threadIdx.x, ty = threadIdx.y;
    int k0 = blockIdx.x * 32, n0 = blockIdx.y * 32;
    #pragma unroll
    for (int i = 0; i < 4; ++i) {
        int kk = ty + i * 8;
        float v = (k0 + kk < FFNN && n0 + tx < FFNN)
                    ? W2[(size_t)(k0 + kk) * FFNN + n0 + tx] : 0.f;
        tile[kk][tx] = v;
    }
    __syncthreads();
    #pragma unroll
    for (int i = 0; i < 4; ++i) {
        int nn = ty + i * 8;
        int k = k0 + tx;
        float v = tile[tx][nn];               // 0 for k>=FFNN or n>=FFNN
        ushort hi = f2b(v);
        float r = v - b2f(hi);
        size_t o = (size_t)(n0 + nn) * 1024 + k;
        TH[o] = hi;
        TL[o] = f2b(r);
    }
}

// ---------- MFMA GEMM: P[z] = doc @ W1slice  (128x64 tile, 384 blocks, dbuf+lds-direct) ----------
// LDS buf layout (ushort): Ah[0..4095]=128x32, Al[4096..8191], Bh[8192..10239]=64x32, Bl[10240..12287]
__global__ __launch_bounds__(256) void k_gemmPm(const ushort* __restrict__ Ah_g,
                                                const ushort* __restrict__ Al_g,
                                                const ushort* __restrict__ Bh_g,
                                                const ushort* __restrict__ Bl_g,
                                                float* __restrict__ Pout) {
    __shared__ ushort LDS[2][12288];
    int tid = threadIdx.x;
    int orig = blockIdx.x;                    // 384 = 8 XCD * 48
    int t = (orig & 7) * 48 + (orig >> 3);
    int pair = t >> 4, colt = t & 15;
    int z = pair >> 3, rowt = pair & 7;
    int row0 = rowt * 128, col0 = colt * 64;
    size_t zoff = (size_t)z * 1024 * D;
    const ushort* Bh_z = Bh_g + zoff;
    const ushort* Bl_z = Bl_g + zoff;
    float* C = Pout + (size_t)z * NW * FFNN;
    int w = tid >> 6, l = tid & 63;
    int wr = w >> 1, wc = w & 1;
    int fr = l & 15, kb = l >> 4;
    int rA = tid >> 2, p = tid & 3;
    int q = p ^ ((rA >> 1) & 3);              // same for rA and rA+64 (32 ≡ 0 mod 4)
    f32x4 acc[4][2] = {};
    int cur = 0;
    #define STAGE_P(d, kt)                                                                  \
        do {                                                                                \
            int kg = (kt) + q * 8;                                                          \
            __builtin_amdgcn_global_load_lds((const uint*)(Ah_g + (size_t)(row0 + rA) * D + kg),      (uint*)&LDS[d][(0 * 256 + tid) * 8], 16, 0, 0); \
            __builtin_amdgcn_global_load_lds((const uint*)(Ah_g + (size_t)(row0 + rA + 64) * D + kg), (uint*)&LDS[d][(1 * 256 + tid) * 8], 16, 0, 0); \
            __builtin_amdgcn_global_load_lds((const uint*)(Al_g + (size_t)(row0 + rA) * D + kg),      (uint*)&LDS[d][(2 * 256 + tid) * 8], 16, 0, 0); \
            __builtin_amdgcn_global_load_lds((const uint*)(Al_g + (size_t)(row0 + rA + 64) * D + kg), (uint*)&LDS[d][(3 * 256 + tid) * 8], 16, 0, 0); \
            __builtin_amdgcn_global_load_lds((const uint*)(Bh_z + (size_t)(col0 + rA) * D + kg),      (uint*)&LDS[d][(4 * 256 + tid) * 8], 16, 0, 0); \
            __builtin_amdgcn_global_load_lds((const uint*)(Bl_z + (size_t)(col0 + rA) * D + kg),      (uint*)&LDS[d][(5 * 256 + tid) * 8], 16, 0, 0); \
        } while (0)
    STAGE_P(0, 0);
    __syncthreads();
    for (int kt = 0; kt < D; kt += 32) {
        if (kt + 32 < D) STAGE_P(cur ^ 1, kt + 32);
        bf16x8 af[4], alf[4], bfr[2], blf[2];
        #pragma unroll
        for (int mt = 0; mt < 4; ++mt) {
            int r = wr * 64 + mt * 16 + fr;
            int sl = (kb ^ ((r >> 1) & 3)) * 8;
            af[mt]  = *(const bf16x8*)&LDS[cur][r * 32 + sl];
            alf[mt] = *(const bf16x8*)&LDS[cur][4096 + r * 32 + sl];
        }
        #pragma unroll
        for (int nt = 0; nt < 2; ++nt) {
            int c = wc * 32 + nt * 16 + fr;
            int sl = (kb ^ ((c >> 1) & 3)) * 8;
            bfr[nt] = *(const bf16x8*)&LDS[cur][8192 + c * 32 + sl];
            blf[nt] = *(const bf16x8*)&LDS[cur][10240 + c * 32 + sl];
        }
        #pragma unroll
        for (int mt = 0; mt < 4; ++mt)
            #pragma unroll
            for (int nt = 0; nt < 2; ++nt) {
                acc[mt][nt] = MFMA16(af[mt], bfr[nt], acc[mt][nt], 0, 0, 0);
                acc[mt][nt] = MFMA16(af[mt], blf[nt], acc[mt][nt], 0, 0, 0);
                acc[mt][nt] = MFMA16(alf[mt], bfr[nt], acc[mt][nt], 0, 0, 0);
            }
        __syncthreads();
        cur ^= 1;
    }
    #pragma unroll
    for (int mt = 0; mt < 4; ++mt)
        #pragma unroll
        for (int nt = 0; nt < 2; ++nt)
            #pragma unroll
            for (int r = 0; r < 4; ++r) {
                int row = row0 + wr * 64 + mt * 16 + kb * 4 + r;
                int col = col0 + wc * 32 + nt * 16 + fr;
                if (col < FFNN) C[(size_t)row * FFNN + col] = acc[mt][nt][r];
            }
}

// ---------- MFMA GEMM2 fused: relu(H1@W2+b2).W3 -> PS (dbuf + global_load_lds) ----------
__global__ __launch_bounds__(256) void k_gemm2m(const ushort* __restrict__ Ah_g,
                                                const ushort* __restrict__ Al_g,
                                                const ushort* __restrict__ Bh_g,
                                                const ushort* __restrict__ Bl_g,
                                                const float* __restrict__ b2,
                                                const float* __restrict__ W3,
                                                float* __restrict__ PS) {
    __shared__ ushort LDS[2][4][128 * 32];
    int tid = threadIdx.x;
    int orig = blockIdx.x;                    // 512 = 8 XCD * 64; XCD owns 8-row band
    int xcd = orig & 7, idx = orig >> 3;
    int rowt = xcd * 8 + (idx & 7), colt = idx >> 3;
    int row0 = rowt * 128, col0 = colt * 128;
    int w = tid >> 6, l = tid & 63;
    int wr = w >> 1, wc = w & 1;
    int fr = l & 15, kb = l >> 4;
    int r0 = tid >> 2, p = tid & 3;
    int r1 = r0 + 64;
    int q0 = p ^ ((r0 >> 1) & 3);
    int q1 = p ^ ((r1 >> 1) & 3);
    int base0 = (w * 64) * 8;
    int base1 = (256 + w * 64) * 8;
    f32x4 acc[4][4] = {};
    int cur = 0;
    #define STAGE_2(d, kt)                                                                  \
        do {                                                                                \
            int kg0 = (kt) + q0 * 8, kg1 = (kt) + q1 * 8;                                   \
            __builtin_amdgcn_global_load_lds((const uint*)(Ah_g + (size_t)(row0 + r0) * 1000 + kg0), (uint*)&LDS[d][0][base0], 16, 0, 0); \
            __builtin_amdgcn_global_load_lds((const uint*)(Al_g + (size_t)(row0 + r0) * 1000 + kg0), (uint*)&LDS[d][1][base0], 16, 0, 0); \
            __builtin_amdgcn_global_load_lds((const uint*)(Bh_g + (size_t)(col0 + r0) * 1024 + kg0), (uint*)&LDS[d][2][base0], 16, 0, 0); \
            __builtin_amdgcn_global_load_lds((const uint*)(Bl_g + (size_t)(col0 + r0) * 1024 + kg0), (uint*)&LDS[d][3][base0], 16, 0, 0); \
            __builtin_amdgcn_global_load_lds((const uint*)(Ah_g + (size_t)(row0 + r1) * 1000 + kg1), (uint*)&LDS[d][0][base1], 16, 0, 0); \
            __builtin_amdgcn_global_load_lds((const uint*)(Al_g + (size_t)(row0 + r1) * 1000 + kg1), (uint*)&LDS[d][1][base1], 16, 0, 0); \
            __builtin_amdgcn_global_load_lds((const uint*)(Bh_g + (size_t)(col0 + r1) * 1024 + kg1), (uint*)&LDS[d][2][base1], 16, 0, 0); \
            __builtin_amdgcn_global_load_lds((const uint*)(Bl_g + (size_t)(col0 + r1) * 1024 + kg1), (uint*)&LDS[d][3][base1], 16, 0, 0); \
        } while (0)
    STAGE_2(0, 0);
    __syncthreads();
    for (int kt = 0; kt < 1024; kt += 32) {
        if (kt + 32 < 1024) STAGE_2(cur ^ 1, kt + 32);
        bf16x8 af[4], alf[4], bfr[4], blf[4];
        #pragma unroll
        for (int mt = 0; mt < 4; ++mt) {
            int r = wr * 64 + mt * 16 + fr;
            int sl = (kb ^ ((r >> 1) & 3)) * 8;
            af[mt]  = *(const bf16x8*)&LDS[cur][0][r * 32 + sl];
            alf[mt] = *(const bf16x8*)&LDS[cur][1][r * 32 + sl];
        }
        #pragma unroll
        for (int nt = 0; nt < 4; ++nt) {
            int c = wc * 64 + nt * 16 + fr;
            int sl = (kb ^ ((c >> 1) & 3)) * 8;
            bfr[nt] = *(const bf16x8*)&LDS[cur][2][c * 32 + sl];
            blf[nt] = *(const bf16x8*)&LDS[cur][3][c * 32 + sl];
        }
        #pragma unroll
        for (int mt = 0; mt < 4; ++mt)
            #pragma unroll
            for (int nt = 0; nt < 4; ++nt) {
                acc[mt][nt] = MFMA16(af[mt], bfr[nt], acc[mt][nt], 0, 0, 0);
                acc[mt][nt] = MFMA16(af[mt], blf[nt], acc[mt][nt], 0, 0, 0);
                acc[mt][nt] = MFMA16(alf[mt], bfr[nt], acc[mt][nt], 0, 0, 0);
            }
        __syncthreads();
        cur ^= 1;
    }
    float w3v[4], b2v[4];
    #pragma unroll
    for (int nt = 0; nt < 4; ++nt) {
        int col = col0 + wc * 64 + nt * 16 + fr;
        bool cv = col < FFNN;
        w3v[nt] = cv ? W3[col] : 0.f;
        b2v[nt] = cv ? b2[col] : 0.f;
    }
    #pragma unroll
    for (int mt = 0; mt < 4; ++mt) {
        #pragma unroll
        for (int r = 0; r < 4; ++r) {
            float pp = 0.f;
            #pragma unroll
            for (int nt = 0; nt < 4; ++nt) {
                float v = fmaxf(acc[mt][nt][r] + b2v[nt], 0.f);
                pp = fmaf(v, w3v[nt], pp);
            }
            pp += __shfl_xor(pp, 1);
            pp += __shfl_xor(pp, 2);
            pp += __shfl_xor(pp, 4);
            pp += __shfl_xor(pp, 8);
            if (fr == 0) {
                int row = row0 + wr * 64 + mt * 16 + kb * 4 + r;
                PS[row * 16 + colt * 2 + wc] = pp;
            }
        }
    }
}

// ---------- h1 assembly (attn fused): softmax + gather P rows + bias + relu -> bf16 hi/lo ----------
__global__ __launch_bounds__(256) void k_h1(const float* __restrict__ P,
                                            const float* __restrict__ P4,
                                            const float* __restrict__ hs,
                                            const float* __restrict__ b1,
                                            const int* __restrict__ starts,
                                            const int* __restrict__ ends,
                                            ushort* __restrict__ H1h,
                                            ushort* __restrict__ H1l) {
    __shared__ float shs[32];
    int s = blockIdx.x;
    int tid = threadIdx.x;
    int st = starts[s], en = ends[s];
    int width = en - st + 1;
    if (tid < MAXW) {
        int idx = st + tid; if (idx > NW - 1) idx = NW - 1;
        shs[tid] = hs[idx];
    }
    __syncthreads();
    // per-thread softmax, identical fp order to the old k_attn
    float v[MAXW];
    float mx = -3.0e38f;
    #pragma unroll
    for (int w = 0; w < MAXW; ++w) {
        float x = shs[w];
        v[w] = (w < width) ? x : -3.0e38f;
        mx = fmaxf(mx, v[w]);
    }
    float sum = 0.f;
    #pragma unroll
    for (int w = 0; w < MAXW; ++w) { v[w] = expf(v[w] - mx); sum += v[w]; }
    float inv = 1.f / sum;
    if (tid >= 250) return;                  // after the only barrier
    const float4* P1r = (const float4*)(P + (size_t)st * FFNN);
    const float4* P2r = (const float4*)(P + (size_t)NW * FFNN + (size_t)en * FFNN);
    const float*  P3  = P + 2 * (size_t)NW * FFNN;
    const float4* P4r = (const float4*)(P4 + (size_t)(width - 1) * FFNN);
    const float4* b1v = (const float4*)b1;
    float4 a = P1r[tid], b = P2r[tid], c = P4r[tid], d = b1v[tid];
    float4 acc = {a.x + b.x + c.x + d.x,
                  a.y + b.y + c.y + d.y,
                  a.z + b.z + c.z + d.z,
                  a.w + b.w + c.w + d.w};
    for (int w = 0; w < width; ++w) {
        float aw = v[w] * inv;
        float4 p3 = ((const float4*)(P3 + (size_t)(st + w) * FFNN))[tid];
        acc.x = fmaf(aw, p3.x, acc.x);
        acc.y = fmaf(aw, p3.y, acc.y);
        acc.z = fmaf(aw, p3.z, acc.z);
        acc.w = fmaf(aw, p3.w, acc.w);
    }
    float rv[4] = {fmaxf(acc.x, 0.f), fmaxf(acc.y, 0.f), fmaxf(acc.z, 0.f), fmaxf(acc.w, 0.f)};
    ushort4 hi, lo;
    ushort* hp = (ushort*)&hi;
    ushort* lp = (ushort*)&lo;
    #pragma unroll
    for (int j = 0; j < 4; ++j) {
        ushort h = f2b(rv[j]);
        float r = rv[j] - b2f(h);
        hp[j] = h;
        lp[j] = f2b(r);
    }
    *(ushort4*)(H1h + (size_t)s * FFNN + tid * 4) = hi;
    *(ushort4*)(H1l + (size_t)s * FFNN + tid * 4) = lo;
}

// ---------- final score: sum 16 partials + b3 ----------
__global__ __launch_bounds__(256) void k_score2(const float* __restrict__ PS,
                                                const float* __restrict__ b3,
                                                float* __restrict__ out) {
    int r = blockIdx.x * 256 + threadIdx.x;
    if (r >= NS) return;
    float s = 0.f;
    #pragma unroll
    for (int b = 0; b < 16; ++b) s += PS[r * 16 + b];
    out[r] = s + b3[0];
}

// ---------- tile-parallel rank ----------
__global__ __launch_bounds__(256) void k_rankA(const float* __restrict__ scores,
                                               int* __restrict__ RANK) {
    __shared__ unsigned long long tile[256];
    int i = blockIdx.x * 256 + threadIdx.x;
    int j = blockIdx.y * 256 + threadIdx.x;
    unsigned uj = __float_as_uint(scores[j]);
    unsigned mj = (uj >> 31) ? ~uj : (uj | 0x80000000u);
    tile[threadIdx.x] = ((unsigned long long)(~mj) << 32) | (unsigned)j;
    __syncthreads();
    unsigned u = __float_as_uint(scores[i]);
    unsigned m = (u >> 31) ? ~u : (u | 0x80000000u);
    unsigned long long key = ((unsigned long long)(~m) << 32) | (unsigned)i;
    int r = 0;
    #pragma unroll 8
    for (int q = 0; q < 256; ++q) r += (tile[q] < key);
    if (r) atomicAdd(&RANK[i], r);
}

// ---------- scatter: pk[RANK[i]] = packed (span, start, end) ----------
__global__ __launch_bounds__(256) void k_rankB(const int* __restrict__ RANK,
                                               const int* __restrict__ starts,
                                               const int* __restrict__ ends,
                                               unsigned long long* __restrict__ pk) {
    int i = blockIdx.x * 256 + threadIdx.x;
    pk[RANK[i]] = ((unsigned long long)(unsigned)i << 32) |
                  ((unsigned)starts[i] << 16) | (unsigned)ends[i];
}

// ---------- parallel pairwise-mask precompute ----------
__global__ __launch_bounds__(64) void k_masks(const unsigned long long* __restrict__ pk,
                                              unsigned long long* __restrict__ MC,
                                              unsigned long long* __restrict__ ME,
                                              unsigned long long* __restrict__ MG) {
    int lane = threadIdx.x;
    int c = blockIdx.x;
    unsigned long long p = pk[c * 64 + lane];
    int s = (int)((p >> 16) & 0xFFFF);
    int e = (int)(p & 0xFFFF);
    unsigned long long conf = 0, eqm = 0, gtm = 0;
    for (int r = 1; r < 64; ++r) {
        int j = (lane + r) & 63;
        int sj = __shfl(s, j);
        int ej = __shfl(e, j);
        unsigned long long bit = 1ull << j;
        bool cross = ((sj > s) & (sj <= e) & (ej > e)) |
                     ((ej >= s) & (ej < e) & (sj < s));
        if (cross) conf |= bit;
        if (sj == s) { if (ej == e) eqm |= bit; else if (ej > e) gtm |= bit; }
    }
    MC[c * 64 + lane] = conf;
    ME[c * 64 + lane] = eqm;
    MG[c * 64 + lane] = gtm;
}

// ---------- greedy crossing-suppression scan (masks precomputed) ----------
__global__ __launch_bounds__(64) void k_scan(const unsigned long long* __restrict__ pk,
                                             const unsigned long long* __restrict__ MC,
                                             const unsigned long long* __restrict__ ME,
                                             const unsigned long long* __restrict__ MG,
                                             int top, int* __restrict__ SEL,
                                             int* __restrict__ SELKEY,
                                             int* __restrict__ CNT) {
    __shared__ int mxs[NW];
    __shared__ int mne[NW];
    __shared__ int mxe[NW];
    int lane = threadIdx.x;
    unsigned long long lower = (1ull << lane) - 1ull;
    for (int p = lane; p < NW; p += 64) { mxs[p] = -1; mne[p] = NW; mxe[p] = -1; }
    __syncthreads();
    int count = 0;
    unsigned long long pc = pk[lane];
    unsigned long long conf = MC[lane], eqm = ME[lane], gtm = MG[lane];
    for (int c = 0; c < NS / 64 && count < top; ++c) {
        unsigned long long pn = 0, cn = 0, en2 = 0, gn = 0;
        if (c + 1 < NS / 64) {
            int o = (c + 1) * 64 + lane;
            pn = pk[o]; cn = MC[o]; en2 = ME[o]; gn = MG[o];
        }
        int span = (int)(pc >> 32);
        int s = (int)((pc >> 16) & 0xFFFF);
        int e = (int)(pc & 0xFFFF);
        int bad = (mxs[e] > s) | (mne[s] < e);
        int g = mxe[s];
        bool gdup = (g == e), ggt = (g > e);
        unsigned long long pending = __ballot(!bad), committed = 0;
        unsigned long long relv = (conf | eqm | gtm) & lower;
        while (pending) {
            bool mine = (pending >> lane) & 1;
            bool ready = mine && ((pending & relv) == 0ull);
            unsigned long long cb = committed & lower;
            bool rej = (cb & conf) != 0ull;
            bool gt_any = ggt || ((cb & gtm) != 0ull);
            bool eq_any = gdup || ((cb & eqm) != 0ull);
            bool acc_now = ready && !rej && !(eq_any && !gt_any);
            committed |= __ballot(acc_now);
            pending &= ~__ballot(ready);
        }
        int allowed = top - count;
        while (__popcll(committed) > allowed)
            committed &= ~(1ull << (63 - __builtin_clzll(committed)));
        if ((committed >> lane) & 1) {
            int pos = count + __popcll(committed & lower);
            SEL[pos] = span;
            SELKEY[pos] = s * NW + e;
            atomicMax(&mxe[s], e);
            #pragma unroll
            for (int k = 0; k < MAXW - 1; ++k) {
                if (k < e - s) {
                    atomicMax(&mxs[s + k], s);
                    atomicMin(&mne[s + 1 + k], e);
                }
            }
        }
        count += __popcll(committed);
        __syncthreads();
        pc = pn; conf = cn; eqm = en2; gtm = gn;
    }
    if (lane == 0) *CNT = count;
}

// ---------- final sort: multi-wave rank sort of the selected spans ----------
__global__ __launch_bounds__(512) void k_sort(const int* __restrict__ SEL,
                                              const int* __restrict__ SELKEY,
                                              const int* __restrict__ CNT,
                                              int top, float* __restrict__ out_idx) {
    __shared__ int keys[512];
    __shared__ int vals[512];
    int cnt = *CNT;
    int r = threadIdx.x;
    if (r < top) {
        keys[r] = (r < cnt) ? SELKEY[r] : NW * NW;
        vals[r] = (r < cnt) ? SEL[r] : -1;
    }
    __syncthreads();
    if (r < top) {
        int kr = keys[r];
        int rank = 0;
        for (int q = 0; q < top; ++q) {
            int kq = keys[q];
            rank += (kq < kr) || (kq == kr && q < r);
        }
        out_idx[rank] = (float)vals[r];
    }
}

extern "C" void kernel_launch(void* const* d_in, const int* in_sizes, int n_in,
                              void* d_out, int out_size, void* d_ws, size_t ws_size,
                              hipStream_t stream) {
    const float* doc = (const float*)d_in[0];
    const float* wwe = (const float*)d_in[1];
    const float* wh  = (const float*)d_in[2];
    const float* bh  = (const float*)d_in[3];
    const float* W1  = (const float*)d_in[4];
    const float* b1  = (const float*)d_in[5];
    const float* W2  = (const float*)d_in[6];
    const float* b2  = (const float*)d_in[7];
    const float* W3  = (const float*)d_in[8];
    const float* b3  = (const float*)d_in[9];
    const int* starts = (const int*)d_in[10];
    const int* ends   = (const int*)d_in[11];
    int top = out_size - NS;                 // 409

    float* ws  = (float*)d_ws;
    float* P   = ws + O_P;
    float* P4  = ws + O_P4;
    float* HS  = ws + O_HS;
    float* PS  = ws + O_PS;
    float* H1R = ws + O_H1R;
    ushort* H1H = (ushort*)H1R;
    ushort* H1L = (ushort*)(H1R + 4096000);
    ushort* W1TH = (ushort*)H1R;
    ushort* W1TL = (ushort*)(H1R + 1179648);
    ushort* DOCH = (ushort*)(H1R + 2359296);
    ushort* DOCL = (ushort*)(H1R + 2752512);
    ushort* W2TH = (ushort*)ws;                          // 1024*1024 ushorts
    ushort* W2TL = (ushort*)(ws + 524288);
    unsigned long long* PK = (unsigned long long*)H1R;   // dead after k_gemm2m
    int* SEL    = (int*)(ws + O_ATT);
    int* SELKEY = SEL + 512;
    int* CNT    = SEL + 1024;
    int* RANK   = SEL + 2048;                            // 8192 ints
    unsigned long long* MC = (unsigned long long*)(ws + O_PS);   // PS dead after k_score2
    unsigned long long* ME = MC + NS;
    unsigned long long* MG = MC + 2 * NS;
    float* outs = (float*)d_out;

    k_head<<<NW / 4, 256, 0, stream>>>(doc, wh, bh, HS);
    k_p4<<<(30 * FFNN + 255) / 256, 256, 0, stream>>>(wwe, W1, P4);

    k_split<<<(NW * D + 255) / 256, 256, 0, stream>>>(doc, DOCH, DOCL, NW * D);
    {
        dim3 g(24, 32, 3), b(32, 8);
        k_tw1<<<g, b, 0, stream>>>(W1, W1TH, W1TL);
    }
    k_gemmPm<<<384, 256, 0, stream>>>(DOCH, DOCL, W1TH, W1TL, P);

    k_h1<<<NS, 256, 0, stream>>>(P, P4, HS, b1, starts, ends, H1H, H1L);

    {
        dim3 g(32, 32), b(32, 8);
        k_tw2<<<g, b, 0, stream>>>(W2, W2TH, W2TL);
    }
    k_gemm2m<<<512, 256, 0, stream>>>(H1H, H1L, W2TH, W2TL, b2, W3, PS);

    k_score2<<<NS / 256, 256, 0, stream>>>(PS, b3, outs);

    hipMemsetAsync(RANK, 0, NS * sizeof(int), stream);
    {
        dim3 g(NS / 256, NS / 256);
        k_rankA<<<g, 256, 0, stream>>>(outs, RANK);
    }
    k_rankB<<<NS / 256, 256, 0, stream>>>(RANK, starts, ends, PK);
    k_masks<<<NS / 64, 64, 0, stream>>>(PK, MC, ME, MG);
    k_scan<<<1, 64, 0, stream>>>(PK, MC, ME, MG, top, SEL, SELKEY, CNT);
    k_sort<<<1, 512, 0, stream>>>(SEL, SELKEY, CNT, top, outs + NS);
}